// Round 11
// baseline (452.002 us; speedup 1.0000x reference)
//
#include <hip/hip_runtime.h>
#include <math.h>

#define TT 8192
#define DZ 32

typedef short bf16x8 __attribute__((ext_vector_type(8)));
typedef _Float16 f16x8 __attribute__((ext_vector_type(8)));
typedef _Float16 f16x4 __attribute__((ext_vector_type(4)));
typedef float f32x4 __attribute__((ext_vector_type(4)));
typedef float f32x16 __attribute__((ext_vector_type(16)));
#define MFMA16F(a,b,c) __builtin_amdgcn_mfma_f32_16x16x32_f16(a,b,c,0,0,0)
#define MFMA32(a,b,c) __builtin_amdgcn_mfma_f32_32x32x16_bf16(a,b,c,0,0,0)

// ---------------- workspace layout (float units) ----------------
#define OFF_QINV   0
#define OFF_Q0INV  1024
#define OFF_AQA    2048
#define OFF_B      3072
#define OFF_P0     4096
#define OFF_PMID   5120
#define OFF_PLAST  6144
#define OFF_LOGSUM 7168
#define OFF_ACT0   8192                     // 2 f16 act slots -> later L (f32, col-major per t)
#define OFF_ACT1   (OFF_ACT0 + 8388608)     // 2 f16 act slots -> later C (f32, X row-major per t)
#define OFF_AAB    (OFF_ACT1 + 8388608)     // cov f32 -> AA in place
#define OFF_XB     (OFF_AAB + 8388608)      // x f16
#define OFF_WB     (OFF_XB + 2097152)       // weights f16
#define OFF_MEANB  (OFF_WB + 5799936)
#define OFF_LAMMU  (OFF_MEANB + 262144)
#define OFF_IBV    (OFF_LAMMU + 262144)

__device__ __forceinline__ unsigned short f2bf(float f) {
    unsigned int u = __float_as_uint(f);
    u += 0x7FFFu + ((u >> 16) & 1u);
    return (unsigned short)(u >> 16);
}
__device__ __forceinline__ float bf2f(unsigned short h) {
    return __uint_as_float(((unsigned int)h) << 16);
}
__device__ __forceinline__ float rlane(float v, int l) {
    return __uint_as_float(__builtin_amdgcn_readlane(__float_as_uint(v), l));
}

// ---------------- fused f32 -> f16 conversion (all tensors, 1 launch) ----------------
struct SplitSeg { const float* src; _Float16* hi; int n; };
struct SplitArgs { SplitSeg seg[9]; };

__global__ __launch_bounds__(256)
void split_all(SplitArgs a)
{
    const SplitSeg sg = a.seg[blockIdx.y];
    const int n4 = sg.n >> 2;
    int i = blockIdx.x * 256 + threadIdx.x;
    if (i >= n4) return;
    float4 v = ((const float4*)sg.src)[i];
    f16x4 hh;
    hh[0] = (_Float16)v.x; hh[1] = (_Float16)v.y;
    hh[2] = (_Float16)v.z; hh[3] = (_Float16)v.w;
    ((f16x4*)sg.hi)[i] = hh;
}

// ---------------- setup: Qinv, Q0inv, AQA, B, priors ----------------
__global__ __launch_bounds__(1024)
void setup_kernel(const float* __restrict__ A, const float* __restrict__ QinvChol,
                  const float* __restrict__ Q0invChol, float* __restrict__ cw)
{
    __shared__ float As[DZ*33], Qc[DZ*33], Q0c[DZ*33], Qi[DZ*33], T1[DZ*33];
    const int tid = threadIdx.x;
    const int i = tid >> 5, j = tid & 31;
    As[i*33+j]  = A[tid];
    Qc[i*33+j]  = QinvChol[tid];
    Q0c[i*33+j] = Q0invChol[tid];
    __syncthreads();
    float qi = 0.f, q0 = 0.f;
    for (int k = 0; k < DZ; ++k) { qi += Qc[i*33+k]*Qc[j*33+k]; q0 += Q0c[i*33+k]*Q0c[j*33+k]; }
    Qi[i*33+j] = qi;
    __syncthreads();
    float t1 = 0.f;
    for (int k = 0; k < DZ; ++k) t1 += Qi[i*33+k]*As[k*33+j];
    T1[i*33+j] = t1;
    __syncthreads();
    float aqa = 0.f, bm = 0.f;
    for (int k = 0; k < DZ; ++k) { aqa += As[k*33+i]*T1[k*33+j]; bm += As[k*33+i]*Qi[k*33+j]; }
    cw[OFF_QINV  + tid] = qi;
    cw[OFF_Q0INV + tid] = q0;
    cw[OFF_AQA   + tid] = aqa;
    cw[OFF_B     + tid] = -bm;
    cw[OFF_P0    + tid] = q0 + aqa;
    cw[OFF_PMID  + tid] = qi + aqa;
    cw[OFF_PLAST + tid] = qi;
    if (tid == 0) cw[OFF_LOGSUM] = 0.f;
}

// ---------------- f16 MFMA GEMM ----------------
__device__ __forceinline__ void stage_tile(const _Float16* src, int rowbase, int Kd,
                                           int k0, _Float16* ldsbase, int w, int lane)
{
#pragma unroll
    for (int inst = 0; inst < 2; ++inst) {
        const int r0  = w * 32 + inst * 16;
        const int row = r0 + (lane >> 2);
        const int g   = (lane & 3) ^ ((row >> 1) & 3);
        const _Float16* gp = src + (size_t)(rowbase + row) * Kd + k0 + g * 8;
        __builtin_amdgcn_global_load_lds(
            (const __attribute__((address_space(1))) void*)gp,
            (__attribute__((address_space(3))) void*)(ldsbase + r0 * 32),
            16, 0, 0);
    }
}

// GEMM body: C = act(A @ W^T + b). OM: 0 f32 out, 1 f16 out.
template<int OM>
__device__ __forceinline__ void mgemm_body(const _Float16* Ah, const _Float16* Wh,
                                           const float* bias, float* outF,
                                           _Float16* outH, int N, int Kd, int relu,
                                           int bn, int bm, _Float16 (*lds)[2][4096])
{
    const int tid = threadIdx.x;
    const int lane = tid & 63, w = tid >> 6;
    const int wm = w >> 1, wn = w & 1;
    const int ln15 = lane & 15, g4 = lane >> 4;

    f32x4 acc[4][4];
#pragma unroll
    for (int i = 0; i < 4; ++i)
#pragma unroll
        for (int j = 0; j < 4; ++j) acc[i][j] = f32x4{0.f,0.f,0.f,0.f};

    const int nt = Kd >> 5;
    stage_tile(Ah, bm*128, Kd, 0, &lds[0][0][0], w, lane);
    stage_tile(Wh, bn*128, Kd, 0, &lds[0][1][0], w, lane);
    __syncthreads();

    int cur = 0;
    for (int t = 0; t < nt; ++t) {
        if (t + 1 < nt) {
            const int k0 = (t + 1) << 5;
            stage_tile(Ah, bm*128, Kd, k0, &lds[cur^1][0][0], w, lane);
            stage_tile(Wh, bn*128, Kd, k0, &lds[cur^1][1][0], w, lane);
        }
        f16x8 fa[4], fwh[4];
#pragma unroll
        for (int fm = 0; fm < 4; ++fm) {
            const int lr = wm*64 + fm*16 + ln15;
            const int off = lr*32 + ((g4 ^ ((lr >> 1) & 3)) << 3);
            fa[fm]  = *(const f16x8*)(&lds[cur][0][0] + off);
        }
#pragma unroll
        for (int fn = 0; fn < 4; ++fn) {
            const int lr = wn*64 + fn*16 + ln15;
            const int off = lr*32 + ((g4 ^ ((lr >> 1) & 3)) << 3);
            fwh[fn] = *(const f16x8*)(&lds[cur][1][0] + off);
        }
#pragma unroll
        for (int fm = 0; fm < 4; ++fm)
#pragma unroll
            for (int fn = 0; fn < 4; ++fn)
                acc[fm][fn] = MFMA16F(fa[fm], fwh[fn], acc[fm][fn]);
        __syncthreads();
        cur ^= 1;
    }

    // epilogue: C/D layout col=lane&15, row=(lane>>4)*4+q  [m89-verified]
#pragma unroll
    for (int fm = 0; fm < 4; ++fm)
#pragma unroll
        for (int fn = 0; fn < 4; ++fn) {
            const int col = bn*128 + wn*64 + fn*16 + ln15;
            const float bv = bias[col];
#pragma unroll
            for (int q = 0; q < 4; ++q) {
                const int row = bm*128 + wm*64 + fm*16 + g4*4 + q;
                float v = acc[fm][fn][q] + bv;
                if (relu) v = fmaxf(v, 0.f);
                if (OM == 0) outF[(size_t)row * N + col] = v;
                else         outH[(size_t)row * N + col] = (_Float16)v;
            }
        }
}

// single-chain GEMM (final cov layer, f32 out)
__global__ __launch_bounds__(256)
void mgemm_f32(const _Float16* __restrict__ Ah, const _Float16* __restrict__ Wh,
               const float* __restrict__ bias, float* __restrict__ outF,
               int N, int Kd)
{
    __shared__ _Float16 lds[2][2][4096];
    mgemm_body<0>(Ah, Wh, bias, outF, nullptr, N, Kd, 0, blockIdx.x, blockIdx.y, lds);
}

// merged mean/cov GEMM: blockIdx.z selects chain (both f16 out, relu)
__global__ __launch_bounds__(256)
void mgemm2(const _Float16* __restrict__ A0, const _Float16* __restrict__ A1,
            const _Float16* __restrict__ W0, const _Float16* __restrict__ W1,
            const float* __restrict__ b0, const float* __restrict__ b1,
            _Float16* __restrict__ o0, _Float16* __restrict__ o1,
            int N, int Kd)
{
    __shared__ _Float16 lds[2][2][4096];
    const int z = blockIdx.z;
    const _Float16* Ah = z ? A1 : A0;
    const _Float16* Wh = z ? W1 : W0;
    const float* bias  = z ? b1 : b0;
    _Float16* outH     = z ? o1 : o0;
    mgemm_body<1>(Ah, Wh, bias, nullptr, outH, N, Kd, 1, blockIdx.x, blockIdx.y, lds);
}

// ---------------- small GEMM (N=32): mean = h3 @ Wm_out^T + b ----------------
__global__ __launch_bounds__(64)
void mgemm_small(const _Float16* __restrict__ Ah, const _Float16* __restrict__ Wh,
                 const float* __restrict__ bias, float* __restrict__ out, int Kd)
{
    const int lane = threadIdx.x;
    const int rm = blockIdx.x * 16;
    const int ln15 = lane & 15, g = lane >> 4;
    const int row = rm + ln15;
    f32x4 acc0 = {0.f,0.f,0.f,0.f}, acc1 = {0.f,0.f,0.f,0.f};
    for (int k0 = 0; k0 < Kd; k0 += 32) {
        const int k = k0 + g*8;
        f16x8 a  = *(const f16x8*)(Ah + (size_t)row*Kd + k);
        f16x8 w0h = *(const f16x8*)(Wh + (size_t)ln15*Kd + k);
        f16x8 w1h = *(const f16x8*)(Wh + (size_t)(16+ln15)*Kd + k);
        acc0 = MFMA16F(a, w0h, acc0);
        acc1 = MFMA16F(a, w1h, acc1);
    }
#pragma unroll
    for (int q = 0; q < 4; ++q) {
        const int r = rm + g*4 + q;
        out[r*DZ + ln15]      = acc0[q] + bias[ln15];
        out[r*DZ + 16 + ln15] = acc1[q] + bias[16 + ln15];
    }
}

// ---------------- build Lam, AA (in place over cov), lamMu ----------------
__global__ __launch_bounds__(256)
void build_blocks_kernel(float* __restrict__ cov, const float* __restrict__ mean,
                         float* __restrict__ lamMu, const float* __restrict__ cw)
{
    const int t = blockIdx.x, tid = threadIdx.x;
    __shared__ float R[DZ*33];
    __shared__ float Lam[DZ*33];
    __shared__ float mn[DZ];
    float* blk = cov + (size_t)t * 1024;
    {
        float4 v = ((const float4*)blk)[tid];
        const int base = tid * 4;
        const int row = base >> 5, col = base & 31;
        R[row*33 + col + 0] = v.x; R[row*33 + col + 1] = v.y;
        R[row*33 + col + 2] = v.z; R[row*33 + col + 3] = v.w;
    }
    if (tid < DZ) mn[tid] = mean[t*DZ + tid];
    __syncthreads();
    const float* P = cw + (t == 0 ? OFF_P0 : (t == TT-1 ? OFF_PLAST : OFF_PMID));
#pragma unroll
    for (int q = 0; q < 4; ++q) {
        const int idx = tid + 256*q;
        const int i = idx >> 5, j = idx & 31;
        float s = 0.f;
#pragma unroll
        for (int k = 0; k < DZ; ++k) s += R[i*33+k] * R[j*33+k];
        Lam[i*33+j] = s;
        blk[idx] = s + P[idx];
    }
    __syncthreads();
    if (tid < DZ) {
        float s = 0.f;
#pragma unroll
        for (int k = 0; k < DZ; ++k) s += Lam[tid*33+k] * mn[k];
        lamMu[t*DZ + tid] = s;
    }
}

// ---------------- chol scan v7 (unchanged math): TLP via K=2 -> 4 waves/SIMD ----------
__device__ __forceinline__ unsigned short f2bf_c(float f) { return f2bf(f); }

#define CHOL_STEP(OWNED)                                                          \
    {                                                                             \
        _Pragma("unroll")                                                         \
        for (int i = 0; i < 32; ++i) s[i] = Apre[i];                              \
        if (t + 1 < own1) {                                                       \
            const float* an = AA + (size_t)(t+1)*1024;                            \
            _Pragma("unroll")                                                     \
            for (int i = 0; i < 32; ++i) Apre[i] = an[i*32 + c];                  \
        }                                                                         \
        const bool doX = (t > t0);                                                \
        if (doX) {                                                                \
            _Pragma("unroll")                                                     \
            for (int i = 0; i < 32; ++i) u[i] = Breg[i];                          \
            _Pragma("unroll")                                                     \
            for (int r = 0; r < 32; ++r) {                                        \
                float x = u[r] * rlane(invd_own, r);                              \
                u[r] = x;                                                         \
                float mm[32];                                                     \
                _Pragma("unroll")                                                 \
                for (int i = r+1; i < 32; ++i) mm[i] = rlane(Lcol[i], r);         \
                _Pragma("unroll")                                                 \
                for (int i = r+1; i < 32; ++i) u[i] = fmaf(-mm[i], x, u[i]);      \
            }                                                                     \
            float f0[8], f1[8];                                                   \
            _Pragma("unroll")                                                     \
            for (int j = 0; j < 8; ++j) {                                         \
                f0[j] = h ? u[8+j]  : u[j];                                       \
                f1[j] = h ? u[24+j] : u[16+j];                                    \
            }                                                                     \
            bf16x8 A0h, A0l, A1h, A1l;                                            \
            _Pragma("unroll")                                                     \
            for (int j = 0; j < 8; ++j) {                                         \
                unsigned short hh0 = f2bf_c(f0[j]);                               \
                A0h[j] = (short)hh0; A0l[j] = (short)f2bf_c(f0[j] - bf2f(hh0));   \
                unsigned short hh1 = f2bf_c(f1[j]);                               \
                A1h[j] = (short)hh1; A1l[j] = (short)f2bf_c(f1[j] - bf2f(hh1));   \
            }                                                                     \
            f32x16 d;                                                             \
            _Pragma("unroll")                                                     \
            for (int q = 0; q < 16; ++q) d[q] = 0.f;                              \
            d = MFMA32(A0h, A0h, d);                                              \
            d = MFMA32(A0h, A0l, d);                                              \
            d = MFMA32(A0l, A0h, d);                                              \
            d = MFMA32(A1h, A1h, d);                                              \
            d = MFMA32(A1h, A1l, d);                                              \
            d = MFMA32(A1l, A1h, d);                                              \
            float dsw[16];                                                        \
            _Pragma("unroll")                                                     \
            for (int q = 0; q < 16; ++q) dsw[q] = __shfl_xor(d[q], 32);           \
            _Pragma("unroll")                                                     \
            for (int i = 0; i < 32; ++i) {                                        \
                const int q  = (i & 3) + ((i >> 3) << 2);                         \
                const int hh = (i >> 2) & 1;                                      \
                s[i] -= (h == hh) ? d[q] : dsw[q];                                \
            }                                                                     \
        }                                                                         \
        float pivk = 1.f;                                                         \
        _Pragma("unroll")                                                         \
        for (int j = 0; j < 32; ++j) {                                            \
            float sjj = rlane(s[j], j);                                           \
            float inv = __builtin_amdgcn_rsqf(sjj);                               \
            pivk = (c == j) ? sjj : pivk;                                         \
            float inv2 = inv * inv;                                               \
            float ljc = (c > j) ? s[j] * inv2 : 0.f;                              \
            invd_own = (c == j) ? inv : invd_own;                                 \
            float mm[32];                                                         \
            _Pragma("unroll")                                                     \
            for (int i = j; i < 32; ++i) mm[i] = rlane(s[i], j);                  \
            _Pragma("unroll")                                                     \
            for (int i = j; i < 32; ++i) s[i] = fmaf(-mm[i], ljc, s[i]);          \
        }                                                                         \
        if (OWNED) logacc += __logf(pivk);                                        \
        _Pragma("unroll")                                                         \
        for (int i = 0; i < 32; ++i) Lcol[i] = s[i] * invd_own;                   \
        if (OWNED) {                                                              \
            float* lt = Lg + (size_t)t*1024 + c*32 + h*16;                        \
            _Pragma("unroll")                                                     \
            for (int q = 0; q < 4; ++q) {                                         \
                float4 v4 = make_float4(h ? Lcol[16+4*q]   : Lcol[4*q],           \
                                        h ? Lcol[16+4*q+1] : Lcol[4*q+1],         \
                                        h ? Lcol[16+4*q+2] : Lcol[4*q+2],         \
                                        h ? Lcol[16+4*q+3] : Lcol[4*q+3]);        \
                *(float4*)(lt + 4*q) = v4;                                        \
            }                                                                     \
            if (doX) {                                                            \
                float* ct = Cg + (size_t)t*1024;                                  \
                _Pragma("unroll")                                                 \
                for (int rr = 0; rr < 16; ++rr) {                                 \
                    float val = h ? u[16+rr] : u[rr];                             \
                    ct[(h*16+rr)*32 + c] = val;                                   \
                }                                                                 \
            }                                                                     \
        }                                                                         \
    }

__global__ __launch_bounds__(64, 4)
void chol_scan7(const float* __restrict__ AA, float* __restrict__ Lg,
                float* __restrict__ Cg, const float* __restrict__ cw,
                float* __restrict__ logsum, int K, int W)
{
    const int lane = threadIdx.x;
    const int c = lane & 31;
    const int h = lane >> 5;
    const int own0 = blockIdx.x * K;
    const int own1 = min(TT, own0 + K);
    const int t0 = max(0, own0 - W);

    float Breg[32], Lcol[32], s[32], u[32], Apre[32];
    float invd_own = 0.f, logacc = 0.f;

#pragma unroll
    for (int i = 0; i < 32; ++i) Breg[i] = cw[OFF_B + i*32 + c];
#pragma unroll
    for (int i = 0; i < 32; ++i) Apre[i] = AA[(size_t)t0*1024 + i*32 + c];

    for (int t = t0; t < own0; ++t) CHOL_STEP(false)
    for (int t = own0; t < own1; ++t) CHOL_STEP(true)

    // lane c holds sum over owned steps of log(pivot_c); butterfly within 32
#pragma unroll
    for (int sft = 16; sft > 0; sft >>= 1) logacc += __shfl_xor(logacc, sft);
    if (lane == 0) atomicAdd(logsum, logacc * 0.5f);
}

// ---------------- chunked forward bidiagonal solve (L col-major, C = X row-major) -------
__global__ __launch_bounds__(64, 4)
void fwd_solve_kernel(const float* __restrict__ Lg, const float* __restrict__ Cg,
                      const float* __restrict__ bv, float* __restrict__ xout,
                      int K, int W)
{
    const int lane = threadIdx.x;
    const int r = lane & 31, h = lane >> 5;
    const int own0 = blockIdx.x * K;
    const int own1 = min(TT, own0 + K);
    const int t0 = max(0, own0 - W);
    float xprev = 0.f;
    for (int t = t0; t < own1; ++t) {
        const float* lt = Lg + (size_t)t * 1024;
        float Lr[32];
#pragma unroll
        for (int j = 0; j < DZ; ++j) Lr[j] = lt[j*32 + r];
        const float inv = __builtin_amdgcn_rcpf(Lr[r]);
        float v = bv[t*DZ + r];
        if (t > t0) {
            const float* ct = Cg + (size_t)t * 1024;
            float Cr[32];
#pragma unroll
            for (int cc = 0; cc < DZ; ++cc) Cr[cc] = ct[cc*32 + r];
#pragma unroll
            for (int cc = 0; cc < DZ; ++cc) v = fmaf(-Cr[cc], __shfl(xprev, cc), v);
        }
        float xv = 0.f;
#pragma unroll
        for (int rr = 0; rr < DZ; ++rr) {
            float cand = v * inv;
            float xb = __shfl(cand, rr);
            if (r == rr) xv = cand;
            if (r > rr) v = fmaf(-Lr[rr], xb, v);
        }
        xprev = xv;
        if (t >= own0 && h == 0) xout[t*DZ + r] = xv;
    }
}

// ---------------- chunked backward solve (two RHS) + sample -----------------------------
__global__ __launch_bounds__(64, 4)
void bwd_solve_kernel(const float* __restrict__ Lg, const float* __restrict__ Cg,
                      const float* __restrict__ b1, const float* __restrict__ b2,
                      float* __restrict__ outSample, int K, int W)
{
    const int lane = threadIdx.x;
    const int k = lane & 31, h = lane >> 5;
    const int own0 = blockIdx.x * K;
    const int own1 = min(TT, own0 + K);
    const int tS = min(TT - 1, own1 - 1 + W);
    float x1p = 0.f, x2p = 0.f;
    for (int t = tS; t >= own0; --t) {
        const float* lt = Lg + (size_t)t * 1024;
        float Lc[32];
#pragma unroll
        for (int q = 0; q < 8; ++q) {
            float4 v4 = *(const float4*)(lt + k*32 + 4*q);
            Lc[4*q] = v4.x; Lc[4*q+1] = v4.y; Lc[4*q+2] = v4.z; Lc[4*q+3] = v4.w;
        }
        const float inv = __builtin_amdgcn_rcpf(Lc[k]);
        float v1 = b1[t*DZ + k], v2 = b2[t*DZ + k];
        if (t < tS) {
            const float* ct = Cg + (size_t)(t+1) * 1024;
            float Cc[32];
#pragma unroll
            for (int q = 0; q < 8; ++q) {
                float4 w4 = *(const float4*)(ct + k*32 + 4*q);
                Cc[4*q] = w4.x; Cc[4*q+1] = w4.y; Cc[4*q+2] = w4.z; Cc[4*q+3] = w4.w;
            }
#pragma unroll
            for (int cc = 0; cc < DZ; ++cc) {
                float a1 = __shfl(x1p, cc), a2 = __shfl(x2p, cc);
                v1 = fmaf(-Cc[cc], a1, v1); v2 = fmaf(-Cc[cc], a2, v2);
            }
        }
        float x1 = 0.f, x2 = 0.f;
#pragma unroll
        for (int rr = DZ-1; rr >= 0; --rr) {
            float c1 = v1 * inv, c2 = v2 * inv;
            float xb1 = __shfl(c1, rr), xb2 = __shfl(c2, rr);
            if (k == rr) { x1 = c1; x2 = c2; }
            if (k < rr) { v1 = fmaf(-Lc[rr], xb1, v1); v2 = fmaf(-Lc[rr], xb2, v2); }
        }
        x1p = x1; x2p = x2;
        if (t >= own0 && h == 0) outSample[t*DZ + k] = x1 + x2;
    }
}

// ---------------- entropy ----------------
__global__ void finalize_kernel(const float* __restrict__ logsum, float* __restrict__ out)
{
    if (threadIdx.x == 0) {
        out[TT*DZ] = (logsum[0] - 2270.3016531274763f) / 409600.0f;
    }
}

// ---------------- launch ----------------
extern "C" void kernel_launch(void* const* d_in, const int* in_sizes, int n_in,
                              void* d_out, int out_size, void* d_ws, size_t ws_size,
                              hipStream_t stream)
{
    (void)in_sizes; (void)n_in; (void)out_size; (void)ws_size;
    const float* x        = (const float*)d_in[0];
    const float* norm     = (const float*)d_in[1];
    const float* A        = (const float*)d_in[2];
    const float* QinvChol = (const float*)d_in[3];
    const float* Q0invChol= (const float*)d_in[4];
    const float* Wm_in = (const float*)d_in[5];  const float* bm_in = (const float*)d_in[6];
    const float* Wm_h1 = (const float*)d_in[7];  const float* bm_h1 = (const float*)d_in[8];
    const float* Wm_h3 = (const float*)d_in[9];  const float* bm_h3 = (const float*)d_in[10];
    const float* Wm_out= (const float*)d_in[11]; const float* bm_out= (const float*)d_in[12];
    const float* Wc_in = (const float*)d_in[13]; const float* bc_in = (const float*)d_in[14];
    const float* Wc_h1 = (const float*)d_in[15]; const float* bc_h1 = (const float*)d_in[16];
    const float* Wc_h3 = (const float*)d_in[17]; const float* bc_h3 = (const float*)d_in[18];
    const float* Wc_out= (const float*)d_in[19]; const float* bc_out= (const float*)d_in[20];

    float* ws    = (float*)d_ws;
    float* out   = (float*)d_out;
    float* cw    = ws;
    float* Lbuf  = ws + OFF_ACT0;
    float* Cbuf  = ws + OFF_ACT1;
    float* covb  = ws + OFF_AAB;
    float* meanb = ws + OFF_MEANB;
    float* lamMu = ws + OFF_LAMMU;
    float* ib    = ws + OFF_IBV;
    float* logsum = ws + OFF_LOGSUM;

    // 4 f16 activation slots, carved from ACT0/ACT1 regions
    _Float16* s0 = (_Float16*)(ws + OFF_ACT0);
    _Float16* s1 = s0 + 8388608;
    _Float16* s2 = (_Float16*)(ws + OFF_ACT1);
    _Float16* s3 = s2 + 8388608;
    _Float16* xh = (_Float16*)(ws + OFF_XB);

    const long OWmi = OFF_WB;
    const long OWm1 = OWmi + 262144;
    const long OWm3 = OWm1 + 1048576;
    const long OWmo = OWm3 + 1048576;
    const long OWci = OWmo + 32768;
    const long OWc1 = OWci + 262144;
    const long OWc3 = OWc1 + 1048576;
    const long OWco = OWc3 + 1048576;
    #define WH(o) ((_Float16*)(ws + (o)))

    setup_kernel<<<dim3(1), dim3(1024), 0, stream>>>(A, QinvChol, Q0invChol, cw);

    SplitArgs sa;
    sa.seg[0] = { x,      xh,       2097152 };
    sa.seg[1] = { Wm_in,  WH(OWmi), 262144 };
    sa.seg[2] = { Wm_h1,  WH(OWm1), 1048576 };
    sa.seg[3] = { Wm_h3,  WH(OWm3), 1048576 };
    sa.seg[4] = { Wm_out, WH(OWmo), 32768 };
    sa.seg[5] = { Wc_in,  WH(OWci), 262144 };
    sa.seg[6] = { Wc_h1,  WH(OWc1), 1048576 };
    sa.seg[7] = { Wc_h3,  WH(OWc3), 1048576 };
    sa.seg[8] = { Wc_out, WH(OWco), 1048576 };
    split_all<<<dim3(2048, 9), dim3(256), 0, stream>>>(sa);

    const dim3 gM(8, 64, 2), blk(256);
    // L1: x -> s0 (mean h1) / s1 (cov h1)
    mgemm2<<<gM, blk, 0, stream>>>(xh, xh, WH(OWmi), WH(OWci), bm_in, bc_in, s0, s1, 1024, 256);
    // L2: s0 -> s2 / s1 -> s3
    mgemm2<<<gM, blk, 0, stream>>>(s0, s1, WH(OWm1), WH(OWc1), bm_h1, bc_h1, s2, s3, 1024, 1024);
    // L3: s2 -> s0 / s3 -> s1
    mgemm2<<<gM, blk, 0, stream>>>(s2, s3, WH(OWm3), WH(OWc3), bm_h3, bc_h3, s0, s1, 1024, 1024);
    // heads
    mgemm_small<<<dim3(512), dim3(64), 0, stream>>>(s0, WH(OWmo), bm_out, meanb, 1024);
    mgemm_f32<<<dim3(8, 64), blk, 0, stream>>>(s1, WH(OWco), bc_out, covb, 1024, 1024);

    build_blocks_kernel<<<dim3(TT), dim3(256), 0, stream>>>(covb, meanb, lamMu, cw);

    // chol: K=2 -> 4096 blocks = 4 waves/SIMD (TLP fills latency stalls); W=2
    chol_scan7<<<dim3(TT/2), dim3(64), 0, stream>>>(covb, Lbuf, Cbuf, cw, logsum, 2, 2);
    // solves: round-9 two-kernel structure (no noise round-trip), K=2 -> 4 waves/SIMD
    fwd_solve_kernel<<<dim3(TT/2), dim3(64), 0, stream>>>(Lbuf, Cbuf, lamMu, ib, 2, 6);
    bwd_solve_kernel<<<dim3(TT/2), dim3(64), 0, stream>>>(Lbuf, Cbuf, ib, norm, out, 2, 6);

    finalize_kernel<<<dim3(1), dim3(64), 0, stream>>>(logsum, out);
}

// Round 12
// 429.599 us; speedup vs baseline: 1.0521x; 1.0521x over previous
//
#include <hip/hip_runtime.h>
#include <math.h>

#define TT 8192
#define DZ 32

typedef short bf16x8 __attribute__((ext_vector_type(8)));
typedef _Float16 f16x8 __attribute__((ext_vector_type(8)));
typedef _Float16 f16x4 __attribute__((ext_vector_type(4)));
typedef float f32x4 __attribute__((ext_vector_type(4)));
typedef float f32x16 __attribute__((ext_vector_type(16)));
#define MFMA16F(a,b,c) __builtin_amdgcn_mfma_f32_16x16x32_f16(a,b,c,0,0,0)
#define MFMA32(a,b,c) __builtin_amdgcn_mfma_f32_32x32x16_bf16(a,b,c,0,0,0)

// ---------------- workspace layout (float units) ----------------
#define OFF_QINV   0
#define OFF_Q0INV  1024
#define OFF_AQA    2048
#define OFF_B      3072
#define OFF_P0     4096
#define OFF_PMID   5120
#define OFF_PLAST  6144
#define OFF_LOGSUM 7168
#define OFF_ACT0   8192                     // 2 f16 act slots -> later L (f32, col-major per t)
#define OFF_ACT1   (OFF_ACT0 + 8388608)     // 2 f16 act slots -> later C (f32, X row-major per t)
#define OFF_AAB    (OFF_ACT1 + 8388608)     // cov f32 -> AA in place
#define OFF_XB     (OFF_AAB + 8388608)      // x f16
#define OFF_WB     (OFF_XB + 2097152)       // weights f16
#define OFF_MEANB  (OFF_WB + 5799936)
#define OFF_LAMMU  (OFF_MEANB + 262144)
#define OFF_IBV    (OFF_LAMMU + 262144)

__device__ __forceinline__ unsigned short f2bf(float f) {
    unsigned int u = __float_as_uint(f);
    u += 0x7FFFu + ((u >> 16) & 1u);
    return (unsigned short)(u >> 16);
}
__device__ __forceinline__ float bf2f(unsigned short h) {
    return __uint_as_float(((unsigned int)h) << 16);
}
__device__ __forceinline__ float rlane(float v, int l) {
    return __uint_as_float(__builtin_amdgcn_readlane(__float_as_uint(v), l));
}

// ---------------- fused f32 -> f16 conversion (all tensors, 1 launch) ----------------
struct SplitSeg { const float* src; _Float16* hi; int n; };
struct SplitArgs { SplitSeg seg[9]; };

__global__ __launch_bounds__(256)
void split_all(SplitArgs a)
{
    const SplitSeg sg = a.seg[blockIdx.y];
    const int n4 = sg.n >> 2;
    int i = blockIdx.x * 256 + threadIdx.x;
    if (i >= n4) return;
    float4 v = ((const float4*)sg.src)[i];
    f16x4 hh;
    hh[0] = (_Float16)v.x; hh[1] = (_Float16)v.y;
    hh[2] = (_Float16)v.z; hh[3] = (_Float16)v.w;
    ((f16x4*)sg.hi)[i] = hh;
}

// ---------------- setup: Qinv, Q0inv, AQA, B, priors ----------------
__global__ __launch_bounds__(1024)
void setup_kernel(const float* __restrict__ A, const float* __restrict__ QinvChol,
                  const float* __restrict__ Q0invChol, float* __restrict__ cw)
{
    __shared__ float As[DZ*33], Qc[DZ*33], Q0c[DZ*33], Qi[DZ*33], T1[DZ*33];
    const int tid = threadIdx.x;
    const int i = tid >> 5, j = tid & 31;
    As[i*33+j]  = A[tid];
    Qc[i*33+j]  = QinvChol[tid];
    Q0c[i*33+j] = Q0invChol[tid];
    __syncthreads();
    float qi = 0.f, q0 = 0.f;
    for (int k = 0; k < DZ; ++k) { qi += Qc[i*33+k]*Qc[j*33+k]; q0 += Q0c[i*33+k]*Q0c[j*33+k]; }
    Qi[i*33+j] = qi;
    __syncthreads();
    float t1 = 0.f;
    for (int k = 0; k < DZ; ++k) t1 += Qi[i*33+k]*As[k*33+j];
    T1[i*33+j] = t1;
    __syncthreads();
    float aqa = 0.f, bm = 0.f;
    for (int k = 0; k < DZ; ++k) { aqa += As[k*33+i]*T1[k*33+j]; bm += As[k*33+i]*Qi[k*33+j]; }
    cw[OFF_QINV  + tid] = qi;
    cw[OFF_Q0INV + tid] = q0;
    cw[OFF_AQA   + tid] = aqa;
    cw[OFF_B     + tid] = -bm;
    cw[OFF_P0    + tid] = q0 + aqa;
    cw[OFF_PMID  + tid] = qi + aqa;
    cw[OFF_PLAST + tid] = qi;
    if (tid == 0) cw[OFF_LOGSUM] = 0.f;
}

// ---------------- f16 MFMA GEMM ----------------
__device__ __forceinline__ void stage_tile(const _Float16* src, int rowbase, int Kd,
                                           int k0, _Float16* ldsbase, int w, int lane)
{
#pragma unroll
    for (int inst = 0; inst < 2; ++inst) {
        const int r0  = w * 32 + inst * 16;
        const int row = r0 + (lane >> 2);
        const int g   = (lane & 3) ^ ((row >> 1) & 3);
        const _Float16* gp = src + (size_t)(rowbase + row) * Kd + k0 + g * 8;
        __builtin_amdgcn_global_load_lds(
            (const __attribute__((address_space(1))) void*)gp,
            (__attribute__((address_space(3))) void*)(ldsbase + r0 * 32),
            16, 0, 0);
    }
}

// GEMM body: C = act(A @ W^T + b). OM: 0 f32 out, 1 f16 out.
template<int OM>
__device__ __forceinline__ void mgemm_body(const _Float16* Ah, const _Float16* Wh,
                                           const float* bias, float* outF,
                                           _Float16* outH, int N, int Kd, int relu,
                                           int bn, int bm, _Float16 (*lds)[2][4096])
{
    const int tid = threadIdx.x;
    const int lane = tid & 63, w = tid >> 6;
    const int wm = w >> 1, wn = w & 1;
    const int ln15 = lane & 15, g4 = lane >> 4;

    f32x4 acc[4][4];
#pragma unroll
    for (int i = 0; i < 4; ++i)
#pragma unroll
        for (int j = 0; j < 4; ++j) acc[i][j] = f32x4{0.f,0.f,0.f,0.f};

    const int nt = Kd >> 5;
    stage_tile(Ah, bm*128, Kd, 0, &lds[0][0][0], w, lane);
    stage_tile(Wh, bn*128, Kd, 0, &lds[0][1][0], w, lane);
    __syncthreads();

    int cur = 0;
    for (int t = 0; t < nt; ++t) {
        if (t + 1 < nt) {
            const int k0 = (t + 1) << 5;
            stage_tile(Ah, bm*128, Kd, k0, &lds[cur^1][0][0], w, lane);
            stage_tile(Wh, bn*128, Kd, k0, &lds[cur^1][1][0], w, lane);
        }
        f16x8 fa[4], fwh[4];
#pragma unroll
        for (int fm = 0; fm < 4; ++fm) {
            const int lr = wm*64 + fm*16 + ln15;
            const int off = lr*32 + ((g4 ^ ((lr >> 1) & 3)) << 3);
            fa[fm]  = *(const f16x8*)(&lds[cur][0][0] + off);
        }
#pragma unroll
        for (int fn = 0; fn < 4; ++fn) {
            const int lr = wn*64 + fn*16 + ln15;
            const int off = lr*32 + ((g4 ^ ((lr >> 1) & 3)) << 3);
            fwh[fn] = *(const f16x8*)(&lds[cur][1][0] + off);
        }
#pragma unroll
        for (int fm = 0; fm < 4; ++fm)
#pragma unroll
            for (int fn = 0; fn < 4; ++fn)
                acc[fm][fn] = MFMA16F(fa[fm], fwh[fn], acc[fm][fn]);
        __syncthreads();
        cur ^= 1;
    }

    // epilogue: C/D layout col=lane&15, row=(lane>>4)*4+q  [m89-verified]
#pragma unroll
    for (int fm = 0; fm < 4; ++fm)
#pragma unroll
        for (int fn = 0; fn < 4; ++fn) {
            const int col = bn*128 + wn*64 + fn*16 + ln15;
            const float bv = bias[col];
#pragma unroll
            for (int q = 0; q < 4; ++q) {
                const int row = bm*128 + wm*64 + fm*16 + g4*4 + q;
                float v = acc[fm][fn][q] + bv;
                if (relu) v = fmaxf(v, 0.f);
                if (OM == 0) outF[(size_t)row * N + col] = v;
                else         outH[(size_t)row * N + col] = (_Float16)v;
            }
        }
}

// single-chain GEMM (final cov layer, f32 out)
__global__ __launch_bounds__(256)
void mgemm_f32(const _Float16* __restrict__ Ah, const _Float16* __restrict__ Wh,
               const float* __restrict__ bias, float* __restrict__ outF,
               int N, int Kd)
{
    __shared__ _Float16 lds[2][2][4096];
    mgemm_body<0>(Ah, Wh, bias, outF, nullptr, N, Kd, 0, blockIdx.x, blockIdx.y, lds);
}

// merged mean/cov GEMM: blockIdx.z selects chain (both f16 out, relu)
__global__ __launch_bounds__(256)
void mgemm2(const _Float16* __restrict__ A0, const _Float16* __restrict__ A1,
            const _Float16* __restrict__ W0, const _Float16* __restrict__ W1,
            const float* __restrict__ b0, const float* __restrict__ b1,
            _Float16* __restrict__ o0, _Float16* __restrict__ o1,
            int N, int Kd)
{
    __shared__ _Float16 lds[2][2][4096];
    const int z = blockIdx.z;
    const _Float16* Ah = z ? A1 : A0;
    const _Float16* Wh = z ? W1 : W0;
    const float* bias  = z ? b1 : b0;
    _Float16* outH     = z ? o1 : o0;
    mgemm_body<1>(Ah, Wh, bias, nullptr, outH, N, Kd, 1, blockIdx.x, blockIdx.y, lds);
}

// ---------------- small GEMM (N=32): mean = h3 @ Wm_out^T + b ----------------
__global__ __launch_bounds__(64)
void mgemm_small(const _Float16* __restrict__ Ah, const _Float16* __restrict__ Wh,
                 const float* __restrict__ bias, float* __restrict__ out, int Kd)
{
    const int lane = threadIdx.x;
    const int rm = blockIdx.x * 16;
    const int ln15 = lane & 15, g = lane >> 4;
    const int row = rm + ln15;
    f32x4 acc0 = {0.f,0.f,0.f,0.f}, acc1 = {0.f,0.f,0.f,0.f};
    for (int k0 = 0; k0 < Kd; k0 += 32) {
        const int k = k0 + g*8;
        f16x8 a  = *(const f16x8*)(Ah + (size_t)row*Kd + k);
        f16x8 w0h = *(const f16x8*)(Wh + (size_t)ln15*Kd + k);
        f16x8 w1h = *(const f16x8*)(Wh + (size_t)(16+ln15)*Kd + k);
        acc0 = MFMA16F(a, w0h, acc0);
        acc1 = MFMA16F(a, w1h, acc1);
    }
#pragma unroll
    for (int q = 0; q < 4; ++q) {
        const int r = rm + g*4 + q;
        out[r*DZ + ln15]      = acc0[q] + bias[ln15];
        out[r*DZ + 16 + ln15] = acc1[q] + bias[16 + ln15];
    }
}

// ---------------- build Lam, AA (in place over cov), lamMu ----------------
__global__ __launch_bounds__(256)
void build_blocks_kernel(float* __restrict__ cov, const float* __restrict__ mean,
                         float* __restrict__ lamMu, const float* __restrict__ cw)
{
    const int t = blockIdx.x, tid = threadIdx.x;
    __shared__ float R[DZ*33];
    __shared__ float Lam[DZ*33];
    __shared__ float mn[DZ];
    float* blk = cov + (size_t)t * 1024;
    {
        float4 v = ((const float4*)blk)[tid];
        const int base = tid * 4;
        const int row = base >> 5, col = base & 31;
        R[row*33 + col + 0] = v.x; R[row*33 + col + 1] = v.y;
        R[row*33 + col + 2] = v.z; R[row*33 + col + 3] = v.w;
    }
    if (tid < DZ) mn[tid] = mean[t*DZ + tid];
    __syncthreads();
    const float* P = cw + (t == 0 ? OFF_P0 : (t == TT-1 ? OFF_PLAST : OFF_PMID));
#pragma unroll
    for (int q = 0; q < 4; ++q) {
        const int idx = tid + 256*q;
        const int i = idx >> 5, j = idx & 31;
        float s = 0.f;
#pragma unroll
        for (int k = 0; k < DZ; ++k) s += R[i*33+k] * R[j*33+k];
        Lam[i*33+j] = s;
        blk[idx] = s + P[idx];
    }
    __syncthreads();
    if (tid < DZ) {
        float s = 0.f;
#pragma unroll
        for (int k = 0; k < DZ; ++k) s += Lam[tid*33+k] * mn[k];
        lamMu[t*DZ + tid] = s;
    }
}

// ---------------- chol scan v7: K=2 TLP, NATURAL regalloc (116 VGPR -> 4 waves/SIMD) ----
// NOTE: __launch_bounds__(64, 4) caps VGPR at 64 -> spills 160-float register state
// (round-11 regression: FETCH 29k->116k KB). Plain (64) gives 116 VGPR <= 128 so 4
// waves/SIMD fit by HW limits without any cap.
__device__ __forceinline__ unsigned short f2bf_c(float f) { return f2bf(f); }

#define CHOL_STEP(OWNED)                                                          \
    {                                                                             \
        _Pragma("unroll")                                                         \
        for (int i = 0; i < 32; ++i) s[i] = Apre[i];                              \
        if (t + 1 < own1) {                                                       \
            const float* an = AA + (size_t)(t+1)*1024;                            \
            _Pragma("unroll")                                                     \
            for (int i = 0; i < 32; ++i) Apre[i] = an[i*32 + c];                  \
        }                                                                         \
        const bool doX = (t > t0);                                                \
        if (doX) {                                                                \
            _Pragma("unroll")                                                     \
            for (int i = 0; i < 32; ++i) u[i] = Breg[i];                          \
            _Pragma("unroll")                                                     \
            for (int r = 0; r < 32; ++r) {                                        \
                float x = u[r] * rlane(invd_own, r);                              \
                u[r] = x;                                                         \
                float mm[32];                                                     \
                _Pragma("unroll")                                                 \
                for (int i = r+1; i < 32; ++i) mm[i] = rlane(Lcol[i], r);         \
                _Pragma("unroll")                                                 \
                for (int i = r+1; i < 32; ++i) u[i] = fmaf(-mm[i], x, u[i]);      \
            }                                                                     \
            float f0[8], f1[8];                                                   \
            _Pragma("unroll")                                                     \
            for (int j = 0; j < 8; ++j) {                                         \
                f0[j] = h ? u[8+j]  : u[j];                                       \
                f1[j] = h ? u[24+j] : u[16+j];                                    \
            }                                                                     \
            bf16x8 A0h, A0l, A1h, A1l;                                            \
            _Pragma("unroll")                                                     \
            for (int j = 0; j < 8; ++j) {                                         \
                unsigned short hh0 = f2bf_c(f0[j]);                               \
                A0h[j] = (short)hh0; A0l[j] = (short)f2bf_c(f0[j] - bf2f(hh0));   \
                unsigned short hh1 = f2bf_c(f1[j]);                               \
                A1h[j] = (short)hh1; A1l[j] = (short)f2bf_c(f1[j] - bf2f(hh1));   \
            }                                                                     \
            f32x16 d;                                                             \
            _Pragma("unroll")                                                     \
            for (int q = 0; q < 16; ++q) d[q] = 0.f;                              \
            d = MFMA32(A0h, A0h, d);                                              \
            d = MFMA32(A0h, A0l, d);                                              \
            d = MFMA32(A0l, A0h, d);                                              \
            d = MFMA32(A1h, A1h, d);                                              \
            d = MFMA32(A1h, A1l, d);                                              \
            d = MFMA32(A1l, A1h, d);                                              \
            float dsw[16];                                                        \
            _Pragma("unroll")                                                     \
            for (int q = 0; q < 16; ++q) dsw[q] = __shfl_xor(d[q], 32);           \
            _Pragma("unroll")                                                     \
            for (int i = 0; i < 32; ++i) {                                        \
                const int q  = (i & 3) + ((i >> 3) << 2);                         \
                const int hh = (i >> 2) & 1;                                      \
                s[i] -= (h == hh) ? d[q] : dsw[q];                                \
            }                                                                     \
        }                                                                         \
        float pivk = 1.f;                                                         \
        _Pragma("unroll")                                                         \
        for (int j = 0; j < 32; ++j) {                                            \
            float sjj = rlane(s[j], j);                                           \
            float inv = __builtin_amdgcn_rsqf(sjj);                               \
            pivk = (c == j) ? sjj : pivk;                                         \
            float inv2 = inv * inv;                                               \
            float ljc = (c > j) ? s[j] * inv2 : 0.f;                              \
            invd_own = (c == j) ? inv : invd_own;                                 \
            float mm[32];                                                         \
            _Pragma("unroll")                                                     \
            for (int i = j; i < 32; ++i) mm[i] = rlane(s[i], j);                  \
            _Pragma("unroll")                                                     \
            for (int i = j; i < 32; ++i) s[i] = fmaf(-mm[i], ljc, s[i]);          \
        }                                                                         \
        if (OWNED) logacc += __logf(pivk);                                        \
        _Pragma("unroll")                                                         \
        for (int i = 0; i < 32; ++i) Lcol[i] = s[i] * invd_own;                   \
        if (OWNED) {                                                              \
            float* lt = Lg + (size_t)t*1024 + c*32 + h*16;                        \
            _Pragma("unroll")                                                     \
            for (int q = 0; q < 4; ++q) {                                         \
                float4 v4 = make_float4(h ? Lcol[16+4*q]   : Lcol[4*q],           \
                                        h ? Lcol[16+4*q+1] : Lcol[4*q+1],         \
                                        h ? Lcol[16+4*q+2] : Lcol[4*q+2],         \
                                        h ? Lcol[16+4*q+3] : Lcol[4*q+3]);        \
                *(float4*)(lt + 4*q) = v4;                                        \
            }                                                                     \
            if (doX) {                                                            \
                float* ct = Cg + (size_t)t*1024;                                  \
                _Pragma("unroll")                                                 \
                for (int rr = 0; rr < 16; ++rr) {                                 \
                    float val = h ? u[16+rr] : u[rr];                             \
                    ct[(h*16+rr)*32 + c] = val;                                   \
                }                                                                 \
            }                                                                     \
        }                                                                         \
    }

__global__ __launch_bounds__(64)
void chol_scan7(const float* __restrict__ AA, float* __restrict__ Lg,
                float* __restrict__ Cg, const float* __restrict__ cw,
                float* __restrict__ logsum, int K, int W)
{
    const int lane = threadIdx.x;
    const int c = lane & 31;
    const int h = lane >> 5;
    const int own0 = blockIdx.x * K;
    const int own1 = min(TT, own0 + K);
    const int t0 = max(0, own0 - W);

    float Breg[32], Lcol[32], s[32], u[32], Apre[32];
    float invd_own = 0.f, logacc = 0.f;

#pragma unroll
    for (int i = 0; i < 32; ++i) Breg[i] = cw[OFF_B + i*32 + c];
#pragma unroll
    for (int i = 0; i < 32; ++i) Apre[i] = AA[(size_t)t0*1024 + i*32 + c];

    for (int t = t0; t < own0; ++t) CHOL_STEP(false)
    for (int t = own0; t < own1; ++t) CHOL_STEP(true)

    // lane c holds sum over owned steps of log(pivot_c); butterfly within 32
#pragma unroll
    for (int sft = 16; sft > 0; sft >>= 1) logacc += __shfl_xor(logacc, sft);
    if (lane == 0) atomicAdd(logsum, logacc * 0.5f);
}

// ---------------- chunked forward bidiagonal solve (L col-major, C = X row-major) -------
__global__ __launch_bounds__(64)
void fwd_solve_kernel(const float* __restrict__ Lg, const float* __restrict__ Cg,
                      const float* __restrict__ bv, float* __restrict__ xout,
                      int K, int W)
{
    const int lane = threadIdx.x;
    const int r = lane & 31, h = lane >> 5;
    const int own0 = blockIdx.x * K;
    const int own1 = min(TT, own0 + K);
    const int t0 = max(0, own0 - W);
    float xprev = 0.f;
    for (int t = t0; t < own1; ++t) {
        const float* lt = Lg + (size_t)t * 1024;
        float Lr[32];
#pragma unroll
        for (int j = 0; j < DZ; ++j) Lr[j] = lt[j*32 + r];
        const float inv = __builtin_amdgcn_rcpf(Lr[r]);
        float v = bv[t*DZ + r];
        if (t > t0) {
            const float* ct = Cg + (size_t)t * 1024;
            float Cr[32];
#pragma unroll
            for (int cc = 0; cc < DZ; ++cc) Cr[cc] = ct[cc*32 + r];
#pragma unroll
            for (int cc = 0; cc < DZ; ++cc) v = fmaf(-Cr[cc], __shfl(xprev, cc), v);
        }
        float xv = 0.f;
#pragma unroll
        for (int rr = 0; rr < DZ; ++rr) {
            float cand = v * inv;
            float xb = __shfl(cand, rr);
            if (r == rr) xv = cand;
            if (r > rr) v = fmaf(-Lr[rr], xb, v);
        }
        xprev = xv;
        if (t >= own0 && h == 0) xout[t*DZ + r] = xv;
    }
}

// ---------------- chunked backward solve (two RHS) + sample -----------------------------
__global__ __launch_bounds__(64)
void bwd_solve_kernel(const float* __restrict__ Lg, const float* __restrict__ Cg,
                      const float* __restrict__ b1, const float* __restrict__ b2,
                      float* __restrict__ outSample, int K, int W)
{
    const int lane = threadIdx.x;
    const int k = lane & 31, h = lane >> 5;
    const int own0 = blockIdx.x * K;
    const int own1 = min(TT, own0 + K);
    const int tS = min(TT - 1, own1 - 1 + W);
    float x1p = 0.f, x2p = 0.f;
    for (int t = tS; t >= own0; --t) {
        const float* lt = Lg + (size_t)t * 1024;
        float Lc[32];
#pragma unroll
        for (int q = 0; q < 8; ++q) {
            float4 v4 = *(const float4*)(lt + k*32 + 4*q);
            Lc[4*q] = v4.x; Lc[4*q+1] = v4.y; Lc[4*q+2] = v4.z; Lc[4*q+3] = v4.w;
        }
        const float inv = __builtin_amdgcn_rcpf(Lc[k]);
        float v1 = b1[t*DZ + k], v2 = b2[t*DZ + k];
        if (t < tS) {
            const float* ct = Cg + (size_t)(t+1) * 1024;
            float Cc[32];
#pragma unroll
            for (int q = 0; q < 8; ++q) {
                float4 w4 = *(const float4*)(ct + k*32 + 4*q);
                Cc[4*q] = w4.x; Cc[4*q+1] = w4.y; Cc[4*q+2] = w4.z; Cc[4*q+3] = w4.w;
            }
#pragma unroll
            for (int cc = 0; cc < DZ; ++cc) {
                float a1 = __shfl(x1p, cc), a2 = __shfl(x2p, cc);
                v1 = fmaf(-Cc[cc], a1, v1); v2 = fmaf(-Cc[cc], a2, v2);
            }
        }
        float x1 = 0.f, x2 = 0.f;
#pragma unroll
        for (int rr = DZ-1; rr >= 0; --rr) {
            float c1 = v1 * inv, c2 = v2 * inv;
            float xb1 = __shfl(c1, rr), xb2 = __shfl(c2, rr);
            if (k == rr) { x1 = c1; x2 = c2; }
            if (k < rr) { v1 = fmaf(-Lc[rr], xb1, v1); v2 = fmaf(-Lc[rr], xb2, v2); }
        }
        x1p = x1; x2p = x2;
        if (t >= own0 && h == 0) outSample[t*DZ + k] = x1 + x2;
    }
}

// ---------------- entropy ----------------
__global__ void finalize_kernel(const float* __restrict__ logsum, float* __restrict__ out)
{
    if (threadIdx.x == 0) {
        out[TT*DZ] = (logsum[0] - 2270.3016531274763f) / 409600.0f;
    }
}

// ---------------- launch ----------------
extern "C" void kernel_launch(void* const* d_in, const int* in_sizes, int n_in,
                              void* d_out, int out_size, void* d_ws, size_t ws_size,
                              hipStream_t stream)
{
    (void)in_sizes; (void)n_in; (void)out_size; (void)ws_size;
    const float* x        = (const float*)d_in[0];
    const float* norm     = (const float*)d_in[1];
    const float* A        = (const float*)d_in[2];
    const float* QinvChol = (const float*)d_in[3];
    const float* Q0invChol= (const float*)d_in[4];
    const float* Wm_in = (const float*)d_in[5];  const float* bm_in = (const float*)d_in[6];
    const float* Wm_h1 = (const float*)d_in[7];  const float* bm_h1 = (const float*)d_in[8];
    const float* Wm_h3 = (const float*)d_in[9];  const float* bm_h3 = (const float*)d_in[10];
    const float* Wm_out= (const float*)d_in[11]; const float* bm_out= (const float*)d_in[12];
    const float* Wc_in = (const float*)d_in[13]; const float* bc_in = (const float*)d_in[14];
    const float* Wc_h1 = (const float*)d_in[15]; const float* bc_h1 = (const float*)d_in[16];
    const float* Wc_h3 = (const float*)d_in[17]; const float* bc_h3 = (const float*)d_in[18];
    const float* Wc_out= (const float*)d_in[19]; const float* bc_out= (const float*)d_in[20];

    float* ws    = (float*)d_ws;
    float* out   = (float*)d_out;
    float* cw    = ws;
    float* Lbuf  = ws + OFF_ACT0;
    float* Cbuf  = ws + OFF_ACT1;
    float* covb  = ws + OFF_AAB;
    float* meanb = ws + OFF_MEANB;
    float* lamMu = ws + OFF_LAMMU;
    float* ib    = ws + OFF_IBV;
    float* logsum = ws + OFF_LOGSUM;

    // 4 f16 activation slots, carved from ACT0/ACT1 regions
    _Float16* s0 = (_Float16*)(ws + OFF_ACT0);
    _Float16* s1 = s0 + 8388608;
    _Float16* s2 = (_Float16*)(ws + OFF_ACT1);
    _Float16* s3 = s2 + 8388608;
    _Float16* xh = (_Float16*)(ws + OFF_XB);

    const long OWmi = OFF_WB;
    const long OWm1 = OWmi + 262144;
    const long OWm3 = OWm1 + 1048576;
    const long OWmo = OWm3 + 1048576;
    const long OWci = OWmo + 32768;
    const long OWc1 = OWci + 262144;
    const long OWc3 = OWc1 + 1048576;
    const long OWco = OWc3 + 1048576;
    #define WH(o) ((_Float16*)(ws + (o)))

    setup_kernel<<<dim3(1), dim3(1024), 0, stream>>>(A, QinvChol, Q0invChol, cw);

    SplitArgs sa;
    sa.seg[0] = { x,      xh,       2097152 };
    sa.seg[1] = { Wm_in,  WH(OWmi), 262144 };
    sa.seg[2] = { Wm_h1,  WH(OWm1), 1048576 };
    sa.seg[3] = { Wm_h3,  WH(OWm3), 1048576 };
    sa.seg[4] = { Wm_out, WH(OWmo), 32768 };
    sa.seg[5] = { Wc_in,  WH(OWci), 262144 };
    sa.seg[6] = { Wc_h1,  WH(OWc1), 1048576 };
    sa.seg[7] = { Wc_h3,  WH(OWc3), 1048576 };
    sa.seg[8] = { Wc_out, WH(OWco), 1048576 };
    split_all<<<dim3(2048, 9), dim3(256), 0, stream>>>(sa);

    const dim3 gM(8, 64, 2), blk(256);
    // L1: x -> s0 (mean h1) / s1 (cov h1)
    mgemm2<<<gM, blk, 0, stream>>>(xh, xh, WH(OWmi), WH(OWci), bm_in, bc_in, s0, s1, 1024, 256);
    // L2: s0 -> s2 / s1 -> s3
    mgemm2<<<gM, blk, 0, stream>>>(s0, s1, WH(OWm1), WH(OWc1), bm_h1, bc_h1, s2, s3, 1024, 1024);
    // L3: s2 -> s0 / s3 -> s1
    mgemm2<<<gM, blk, 0, stream>>>(s2, s3, WH(OWm3), WH(OWc3), bm_h3, bc_h3, s0, s1, 1024, 1024);
    // heads
    mgemm_small<<<dim3(512), dim3(64), 0, stream>>>(s0, WH(OWmo), bm_out, meanb, 1024);
    mgemm_f32<<<dim3(8, 64), blk, 0, stream>>>(s1, WH(OWco), bc_out, covb, 1024, 1024);

    build_blocks_kernel<<<dim3(TT), dim3(256), 0, stream>>>(covb, meanb, lamMu, cw);

    // chol: K=2 -> 4096 blocks; natural 116 VGPR -> 4 waves/SIMD by HW limit (no cap!)
    chol_scan7<<<dim3(TT/2), dim3(64), 0, stream>>>(covb, Lbuf, Cbuf, cw, logsum, 2, 2);
    fwd_solve_kernel<<<dim3(TT/2), dim3(64), 0, stream>>>(Lbuf, Cbuf, lamMu, ib, 2, 6);
    bwd_solve_kernel<<<dim3(TT/2), dim3(64), 0, stream>>>(Lbuf, Cbuf, ib, norm, out, 2, 6);

    finalize_kernel<<<dim3(1), dim3(64), 0, stream>>>(logsum, out);
}

// Round 13
// 415.638 us; speedup vs baseline: 1.0875x; 1.0336x over previous
//
#include <hip/hip_runtime.h>
#include <math.h>

#define TT 8192
#define DZ 32

typedef short bf16x8 __attribute__((ext_vector_type(8)));
typedef _Float16 f16x8 __attribute__((ext_vector_type(8)));
typedef _Float16 f16x4 __attribute__((ext_vector_type(4)));
typedef float f32x4 __attribute__((ext_vector_type(4)));
typedef float f32x16 __attribute__((ext_vector_type(16)));
#define MFMA16F(a,b,c) __builtin_amdgcn_mfma_f32_16x16x32_f16(a,b,c,0,0,0)
#define MFMA32(a,b,c) __builtin_amdgcn_mfma_f32_32x32x16_bf16(a,b,c,0,0,0)

// ---------------- workspace layout (float units) ----------------
#define OFF_QINV   0
#define OFF_Q0INV  1024
#define OFF_AQA    2048
#define OFF_B      3072
#define OFF_P0     4096
#define OFF_PMID   5120
#define OFF_PLAST  6144
#define OFF_LOGSUM 7168
#define OFF_ACT0   8192                     // 2 f16 act slots -> later L (f32, col-major per t)
#define OFF_ACT1   (OFF_ACT0 + 8388608)     // 2 f16 act slots -> later C (f32, X row-major per t)
#define OFF_AAB    (OFF_ACT1 + 8388608)     // cov f32 -> AA in place
#define OFF_XB     (OFF_AAB + 8388608)      // x f16
#define OFF_WB     (OFF_XB + 2097152)       // weights f16
#define OFF_MEANB  (OFF_WB + 5799936)
#define OFF_LAMMU  (OFF_MEANB + 262144)
#define OFF_IBV    (OFF_LAMMU + 262144)

__device__ __forceinline__ unsigned short f2bf(float f) {
    unsigned int u = __float_as_uint(f);
    u += 0x7FFFu + ((u >> 16) & 1u);
    return (unsigned short)(u >> 16);
}
__device__ __forceinline__ float bf2f(unsigned short h) {
    return __uint_as_float(((unsigned int)h) << 16);
}
__device__ __forceinline__ float rlane(float v, int l) {
    return __uint_as_float(__builtin_amdgcn_readlane(__float_as_uint(v), l));
}

// ---------------- fused f32 -> f16 conversion (all tensors, 1 launch) ----------------
struct SplitSeg { const float* src; _Float16* hi; int n; };
struct SplitArgs { SplitSeg seg[9]; };

__global__ __launch_bounds__(256)
void split_all(SplitArgs a)
{
    const SplitSeg sg = a.seg[blockIdx.y];
    const int n4 = sg.n >> 2;
    int i = blockIdx.x * 256 + threadIdx.x;
    if (i >= n4) return;
    float4 v = ((const float4*)sg.src)[i];
    f16x4 hh;
    hh[0] = (_Float16)v.x; hh[1] = (_Float16)v.y;
    hh[2] = (_Float16)v.z; hh[3] = (_Float16)v.w;
    ((f16x4*)sg.hi)[i] = hh;
}

// ---------------- setup: Qinv, Q0inv, AQA, B, priors ----------------
__global__ __launch_bounds__(1024)
void setup_kernel(const float* __restrict__ A, const float* __restrict__ QinvChol,
                  const float* __restrict__ Q0invChol, float* __restrict__ cw)
{
    __shared__ float As[DZ*33], Qc[DZ*33], Q0c[DZ*33], Qi[DZ*33], T1[DZ*33];
    const int tid = threadIdx.x;
    const int i = tid >> 5, j = tid & 31;
    As[i*33+j]  = A[tid];
    Qc[i*33+j]  = QinvChol[tid];
    Q0c[i*33+j] = Q0invChol[tid];
    __syncthreads();
    float qi = 0.f, q0 = 0.f;
    for (int k = 0; k < DZ; ++k) { qi += Qc[i*33+k]*Qc[j*33+k]; q0 += Q0c[i*33+k]*Q0c[j*33+k]; }
    Qi[i*33+j] = qi;
    __syncthreads();
    float t1 = 0.f;
    for (int k = 0; k < DZ; ++k) t1 += Qi[i*33+k]*As[k*33+j];
    T1[i*33+j] = t1;
    __syncthreads();
    float aqa = 0.f, bm = 0.f;
    for (int k = 0; k < DZ; ++k) { aqa += As[k*33+i]*T1[k*33+j]; bm += As[k*33+i]*Qi[k*33+j]; }
    cw[OFF_QINV  + tid] = qi;
    cw[OFF_Q0INV + tid] = q0;
    cw[OFF_AQA   + tid] = aqa;
    cw[OFF_B     + tid] = -bm;
    cw[OFF_P0    + tid] = q0 + aqa;
    cw[OFF_PMID  + tid] = qi + aqa;
    cw[OFF_PLAST + tid] = qi;
    if (tid == 0) cw[OFF_LOGSUM] = 0.f;
}

// ---------------- f16 MFMA GEMM ----------------
__device__ __forceinline__ void stage_tile(const _Float16* src, int rowbase, int Kd,
                                           int k0, _Float16* ldsbase, int w, int lane)
{
#pragma unroll
    for (int inst = 0; inst < 2; ++inst) {
        const int r0  = w * 32 + inst * 16;
        const int row = r0 + (lane >> 2);
        const int g   = (lane & 3) ^ ((row >> 1) & 3);
        const _Float16* gp = src + (size_t)(rowbase + row) * Kd + k0 + g * 8;
        __builtin_amdgcn_global_load_lds(
            (const __attribute__((address_space(1))) void*)gp,
            (__attribute__((address_space(3))) void*)(ldsbase + r0 * 32),
            16, 0, 0);
    }
}

// GEMM body: C = act(A @ W^T + b). OM: 0 f32 out, 1 f16 out.
template<int OM>
__device__ __forceinline__ void mgemm_body(const _Float16* Ah, const _Float16* Wh,
                                           const float* bias, float* outF,
                                           _Float16* outH, int N, int Kd, int relu,
                                           int bn, int bm, _Float16 (*lds)[2][4096])
{
    const int tid = threadIdx.x;
    const int lane = tid & 63, w = tid >> 6;
    const int wm = w >> 1, wn = w & 1;
    const int ln15 = lane & 15, g4 = lane >> 4;

    f32x4 acc[4][4];
#pragma unroll
    for (int i = 0; i < 4; ++i)
#pragma unroll
        for (int j = 0; j < 4; ++j) acc[i][j] = f32x4{0.f,0.f,0.f,0.f};

    const int nt = Kd >> 5;
    stage_tile(Ah, bm*128, Kd, 0, &lds[0][0][0], w, lane);
    stage_tile(Wh, bn*128, Kd, 0, &lds[0][1][0], w, lane);
    __syncthreads();

    int cur = 0;
    for (int t = 0; t < nt; ++t) {
        if (t + 1 < nt) {
            const int k0 = (t + 1) << 5;
            stage_tile(Ah, bm*128, Kd, k0, &lds[cur^1][0][0], w, lane);
            stage_tile(Wh, bn*128, Kd, k0, &lds[cur^1][1][0], w, lane);
        }
        f16x8 fa[4], fwh[4];
#pragma unroll
        for (int fm = 0; fm < 4; ++fm) {
            const int lr = wm*64 + fm*16 + ln15;
            const int off = lr*32 + ((g4 ^ ((lr >> 1) & 3)) << 3);
            fa[fm]  = *(const f16x8*)(&lds[cur][0][0] + off);
        }
#pragma unroll
        for (int fn = 0; fn < 4; ++fn) {
            const int lr = wn*64 + fn*16 + ln15;
            const int off = lr*32 + ((g4 ^ ((lr >> 1) & 3)) << 3);
            fwh[fn] = *(const f16x8*)(&lds[cur][1][0] + off);
        }
#pragma unroll
        for (int fm = 0; fm < 4; ++fm)
#pragma unroll
            for (int fn = 0; fn < 4; ++fn)
                acc[fm][fn] = MFMA16F(fa[fm], fwh[fn], acc[fm][fn]);
        __syncthreads();
        cur ^= 1;
    }

    // epilogue: C/D layout col=lane&15, row=(lane>>4)*4+q  [m89-verified]
#pragma unroll
    for (int fm = 0; fm < 4; ++fm)
#pragma unroll
        for (int fn = 0; fn < 4; ++fn) {
            const int col = bn*128 + wn*64 + fn*16 + ln15;
            const float bv = bias[col];
#pragma unroll
            for (int q = 0; q < 4; ++q) {
                const int row = bm*128 + wm*64 + fm*16 + g4*4 + q;
                float v = acc[fm][fn][q] + bv;
                if (relu) v = fmaxf(v, 0.f);
                if (OM == 0) outF[(size_t)row * N + col] = v;
                else         outH[(size_t)row * N + col] = (_Float16)v;
            }
        }
}

// single-chain GEMM (final cov layer, f32 out)
__global__ __launch_bounds__(256)
void mgemm_f32(const _Float16* __restrict__ Ah, const _Float16* __restrict__ Wh,
               const float* __restrict__ bias, float* __restrict__ outF,
               int N, int Kd)
{
    __shared__ _Float16 lds[2][2][4096];
    mgemm_body<0>(Ah, Wh, bias, outF, nullptr, N, Kd, 0, blockIdx.x, blockIdx.y, lds);
}

// merged mean/cov GEMM: blockIdx.z selects chain (both f16 out, relu)
__global__ __launch_bounds__(256)
void mgemm2(const _Float16* __restrict__ A0, const _Float16* __restrict__ A1,
            const _Float16* __restrict__ W0, const _Float16* __restrict__ W1,
            const float* __restrict__ b0, const float* __restrict__ b1,
            _Float16* __restrict__ o0, _Float16* __restrict__ o1,
            int N, int Kd)
{
    __shared__ _Float16 lds[2][2][4096];
    const int z = blockIdx.z;
    const _Float16* Ah = z ? A1 : A0;
    const _Float16* Wh = z ? W1 : W0;
    const float* bias  = z ? b1 : b0;
    _Float16* outH     = z ? o1 : o0;
    mgemm_body<1>(Ah, Wh, bias, nullptr, outH, N, Kd, 1, blockIdx.x, blockIdx.y, lds);
}

// ---------------- small GEMM (N=32): mean = h3 @ Wm_out^T + b ----------------
__global__ __launch_bounds__(64)
void mgemm_small(const _Float16* __restrict__ Ah, const _Float16* __restrict__ Wh,
                 const float* __restrict__ bias, float* __restrict__ out, int Kd)
{
    const int lane = threadIdx.x;
    const int rm = blockIdx.x * 16;
    const int ln15 = lane & 15, g = lane >> 4;
    const int row = rm + ln15;
    f32x4 acc0 = {0.f,0.f,0.f,0.f}, acc1 = {0.f,0.f,0.f,0.f};
    for (int k0 = 0; k0 < Kd; k0 += 32) {
        const int k = k0 + g*8;
        f16x8 a  = *(const f16x8*)(Ah + (size_t)row*Kd + k);
        f16x8 w0h = *(const f16x8*)(Wh + (size_t)ln15*Kd + k);
        f16x8 w1h = *(const f16x8*)(Wh + (size_t)(16+ln15)*Kd + k);
        acc0 = MFMA16F(a, w0h, acc0);
        acc1 = MFMA16F(a, w1h, acc1);
    }
#pragma unroll
    for (int q = 0; q < 4; ++q) {
        const int r = rm + g*4 + q;
        out[r*DZ + ln15]      = acc0[q] + bias[ln15];
        out[r*DZ + 16 + ln15] = acc1[q] + bias[16 + ln15];
    }
}

// ---------------- build Lam, AA (in place over cov), lamMu ----------------
__global__ __launch_bounds__(256)
void build_blocks_kernel(float* __restrict__ cov, const float* __restrict__ mean,
                         float* __restrict__ lamMu, const float* __restrict__ cw)
{
    const int t = blockIdx.x, tid = threadIdx.x;
    __shared__ float R[DZ*33];
    __shared__ float Lam[DZ*33];
    __shared__ float mn[DZ];
    float* blk = cov + (size_t)t * 1024;
    {
        float4 v = ((const float4*)blk)[tid];
        const int base = tid * 4;
        const int row = base >> 5, col = base & 31;
        R[row*33 + col + 0] = v.x; R[row*33 + col + 1] = v.y;
        R[row*33 + col + 2] = v.z; R[row*33 + col + 3] = v.w;
    }
    if (tid < DZ) mn[tid] = mean[t*DZ + tid];
    __syncthreads();
    const float* P = cw + (t == 0 ? OFF_P0 : (t == TT-1 ? OFF_PLAST : OFF_PMID));
#pragma unroll
    for (int q = 0; q < 4; ++q) {
        const int idx = tid + 256*q;
        const int i = idx >> 5, j = idx & 31;
        float s = 0.f;
#pragma unroll
        for (int k = 0; k < DZ; ++k) s += R[i*33+k] * R[j*33+k];
        Lam[i*33+j] = s;
        blk[idx] = s + P[idx];
    }
    __syncthreads();
    if (tid < DZ) {
        float s = 0.f;
#pragma unroll
        for (int k = 0; k < DZ; ++k) s += Lam[tid*33+k] * mn[k];
        lamMu[t*DZ + tid] = s;
    }
}

// ---------------- chol scan v8: REGISTER DIET for 4 waves/SIMD ----------
// Theory (r12): waves/SIMD = floor(512 / unified-regs). v7's ~180-190 regs
// (Breg+Apre+mm temporaries + acc) capped residency at 2 waves/SIMD regardless
// of grid. Diet: B in LDS (block-constant), no Apre prefetch (direct s load at
// step top, consumed only AFTER the MFMA -> latency self-hides), no mm batching
// (proven neutral in r10). Peak live ~110 regs -> 4 waves/SIMD at K=2.
__device__ __forceinline__ unsigned short f2bf_c(float f) { return f2bf(f); }

#define CHOL_STEP2(OWNED)                                                         \
    {                                                                             \
        const float* at = AA + (size_t)t * 1024;                                  \
        _Pragma("unroll")                                                         \
        for (int i = 0; i < 32; ++i) s[i] = at[i*32 + c];                         \
        const bool doX = (t > t0);                                                \
        if (doX) {                                                                \
            _Pragma("unroll")                                                     \
            for (int i = 0; i < 32; ++i) u[i] = Bs[i*32 + c];                     \
            _Pragma("unroll")                                                     \
            for (int r = 0; r < 32; ++r) {                                        \
                float x = u[r] * rlane(invd_own, r);                              \
                u[r] = x;                                                         \
                _Pragma("unroll")                                                 \
                for (int i = r+1; i < 32; ++i)                                    \
                    u[i] = fmaf(-rlane(Lcol[i], r), x, u[i]);                     \
            }                                                                     \
            if (OWNED) {                                                          \
                float* ct = Cg + (size_t)t*1024;                                  \
                _Pragma("unroll")                                                 \
                for (int rr = 0; rr < 16; ++rr) {                                 \
                    float val = h ? u[16+rr] : u[rr];                             \
                    ct[(h*16+rr)*32 + c] = val;                                   \
                }                                                                 \
            }                                                                     \
            float f0[8], f1[8];                                                   \
            _Pragma("unroll")                                                     \
            for (int j = 0; j < 8; ++j) {                                         \
                f0[j] = h ? u[8+j]  : u[j];                                       \
                f1[j] = h ? u[24+j] : u[16+j];                                    \
            }                                                                     \
            bf16x8 A0h, A0l, A1h, A1l;                                            \
            _Pragma("unroll")                                                     \
            for (int j = 0; j < 8; ++j) {                                         \
                unsigned short hh0 = f2bf_c(f0[j]);                               \
                A0h[j] = (short)hh0; A0l[j] = (short)f2bf_c(f0[j] - bf2f(hh0));   \
                unsigned short hh1 = f2bf_c(f1[j]);                               \
                A1h[j] = (short)hh1; A1l[j] = (short)f2bf_c(f1[j] - bf2f(hh1));   \
            }                                                                     \
            f32x16 d;                                                             \
            _Pragma("unroll")                                                     \
            for (int q = 0; q < 16; ++q) d[q] = 0.f;                              \
            d = MFMA32(A0h, A0h, d);                                              \
            d = MFMA32(A0h, A0l, d);                                              \
            d = MFMA32(A0l, A0h, d);                                              \
            d = MFMA32(A1h, A1h, d);                                              \
            d = MFMA32(A1h, A1l, d);                                              \
            d = MFMA32(A1l, A1h, d);                                              \
            float dsw[16];                                                        \
            _Pragma("unroll")                                                     \
            for (int q = 0; q < 16; ++q) dsw[q] = __shfl_xor(d[q], 32);           \
            _Pragma("unroll")                                                     \
            for (int i = 0; i < 32; ++i) {                                        \
                const int q  = (i & 3) + ((i >> 3) << 2);                         \
                const int hh = (i >> 2) & 1;                                      \
                s[i] -= (h == hh) ? d[q] : dsw[q];                                \
            }                                                                     \
        }                                                                         \
        float pivk = 1.f;                                                         \
        _Pragma("unroll")                                                         \
        for (int j = 0; j < 32; ++j) {                                            \
            float sjj = rlane(s[j], j);                                           \
            float inv = __builtin_amdgcn_rsqf(sjj);                               \
            pivk = (c == j) ? sjj : pivk;                                         \
            float inv2 = inv * inv;                                               \
            float ljc = (c > j) ? s[j] * inv2 : 0.f;                              \
            invd_own = (c == j) ? inv : invd_own;                                 \
            _Pragma("unroll")                                                     \
            for (int i = j; i < 32; ++i) s[i] = fmaf(-rlane(s[i], j), ljc, s[i]); \
        }                                                                         \
        if (OWNED) logacc += __logf(pivk);                                        \
        _Pragma("unroll")                                                         \
        for (int i = 0; i < 32; ++i) Lcol[i] = s[i] * invd_own;                   \
        if (OWNED) {                                                              \
            float* lt = Lg + (size_t)t*1024 + c*32 + h*16;                        \
            _Pragma("unroll")                                                     \
            for (int q = 0; q < 4; ++q) {                                         \
                float4 v4 = make_float4(h ? Lcol[16+4*q]   : Lcol[4*q],           \
                                        h ? Lcol[16+4*q+1] : Lcol[4*q+1],         \
                                        h ? Lcol[16+4*q+2] : Lcol[4*q+2],         \
                                        h ? Lcol[16+4*q+3] : Lcol[4*q+3]);        \
                *(float4*)(lt + 4*q) = v4;                                        \
            }                                                                     \
        }                                                                         \
    }

__global__ __launch_bounds__(64)
void chol_scan8(const float* __restrict__ AA, float* __restrict__ Lg,
                float* __restrict__ Cg, const float* __restrict__ cw,
                float* __restrict__ logsum, int K, int W)
{
    const int lane = threadIdx.x;
    const int c = lane & 31;
    const int h = lane >> 5;
    const int own0 = blockIdx.x * K;
    const int own1 = min(TT, own0 + K);
    const int t0 = max(0, own0 - W);

    __shared__ float Bs[1024];
#pragma unroll
    for (int i = 0; i < 16; ++i) Bs[i*64 + lane] = cw[OFF_B + i*64 + lane];
    __syncthreads();

    float Lcol[32], s[32], u[32];
    float invd_own = 0.f, logacc = 0.f;

    for (int t = t0; t < own0; ++t) CHOL_STEP2(false)
    for (int t = own0; t < own1; ++t) CHOL_STEP2(true)

    // lane c holds sum over owned steps of log(pivot_c); butterfly within 32
#pragma unroll
    for (int sft = 16; sft > 0; sft >>= 1) logacc += __shfl_xor(logacc, sft);
    if (lane == 0) atomicAdd(logsum, logacc * 0.5f);
}

// ---------------- chunked forward bidiagonal solve (L col-major, C = X row-major) -------
__global__ __launch_bounds__(64)
void fwd_solve_kernel(const float* __restrict__ Lg, const float* __restrict__ Cg,
                      const float* __restrict__ bv, float* __restrict__ xout,
                      int K, int W)
{
    const int lane = threadIdx.x;
    const int r = lane & 31, h = lane >> 5;
    const int own0 = blockIdx.x * K;
    const int own1 = min(TT, own0 + K);
    const int t0 = max(0, own0 - W);
    float xprev = 0.f;
    for (int t = t0; t < own1; ++t) {
        const float* lt = Lg + (size_t)t * 1024;
        float Lr[32];
#pragma unroll
        for (int j = 0; j < DZ; ++j) Lr[j] = lt[j*32 + r];
        const float inv = __builtin_amdgcn_rcpf(Lr[r]);
        float v = bv[t*DZ + r];
        if (t > t0) {
            const float* ct = Cg + (size_t)t * 1024;
            float Cr[32];
#pragma unroll
            for (int cc = 0; cc < DZ; ++cc) Cr[cc] = ct[cc*32 + r];
#pragma unroll
            for (int cc = 0; cc < DZ; ++cc) v = fmaf(-Cr[cc], __shfl(xprev, cc), v);
        }
        float xv = 0.f;
#pragma unroll
        for (int rr = 0; rr < DZ; ++rr) {
            float cand = v * inv;
            float xb = __shfl(cand, rr);
            if (r == rr) xv = cand;
            if (r > rr) v = fmaf(-Lr[rr], xb, v);
        }
        xprev = xv;
        if (t >= own0 && h == 0) xout[t*DZ + r] = xv;
    }
}

// ---------------- chunked backward solve (two RHS) + sample -----------------------------
__global__ __launch_bounds__(64)
void bwd_solve_kernel(const float* __restrict__ Lg, const float* __restrict__ Cg,
                      const float* __restrict__ b1, const float* __restrict__ b2,
                      float* __restrict__ outSample, int K, int W)
{
    const int lane = threadIdx.x;
    const int k = lane & 31, h = lane >> 5;
    const int own0 = blockIdx.x * K;
    const int own1 = min(TT, own0 + K);
    const int tS = min(TT - 1, own1 - 1 + W);
    float x1p = 0.f, x2p = 0.f;
    for (int t = tS; t >= own0; --t) {
        const float* lt = Lg + (size_t)t * 1024;
        float Lc[32];
#pragma unroll
        for (int q = 0; q < 8; ++q) {
            float4 v4 = *(const float4*)(lt + k*32 + 4*q);
            Lc[4*q] = v4.x; Lc[4*q+1] = v4.y; Lc[4*q+2] = v4.z; Lc[4*q+3] = v4.w;
        }
        const float inv = __builtin_amdgcn_rcpf(Lc[k]);
        float v1 = b1[t*DZ + k], v2 = b2[t*DZ + k];
        if (t < tS) {
            const float* ct = Cg + (size_t)(t+1) * 1024;
            float Cc[32];
#pragma unroll
            for (int q = 0; q < 8; ++q) {
                float4 w4 = *(const float4*)(ct + k*32 + 4*q);
                Cc[4*q] = w4.x; Cc[4*q+1] = w4.y; Cc[4*q+2] = w4.z; Cc[4*q+3] = w4.w;
            }
#pragma unroll
            for (int cc = 0; cc < DZ; ++cc) {
                float a1 = __shfl(x1p, cc), a2 = __shfl(x2p, cc);
                v1 = fmaf(-Cc[cc], a1, v1); v2 = fmaf(-Cc[cc], a2, v2);
            }
        }
        float x1 = 0.f, x2 = 0.f;
#pragma unroll
        for (int rr = DZ-1; rr >= 0; --rr) {
            float c1 = v1 * inv, c2 = v2 * inv;
            float xb1 = __shfl(c1, rr), xb2 = __shfl(c2, rr);
            if (k == rr) { x1 = c1; x2 = c2; }
            if (k < rr) { v1 = fmaf(-Lc[rr], xb1, v1); v2 = fmaf(-Lc[rr], xb2, v2); }
        }
        x1p = x1; x2p = x2;
        if (t >= own0 && h == 0) outSample[t*DZ + k] = x1 + x2;
    }
}

// ---------------- entropy ----------------
__global__ void finalize_kernel(const float* __restrict__ logsum, float* __restrict__ out)
{
    if (threadIdx.x == 0) {
        out[TT*DZ] = (logsum[0] - 2270.3016531274763f) / 409600.0f;
    }
}

// ---------------- launch ----------------
extern "C" void kernel_launch(void* const* d_in, const int* in_sizes, int n_in,
                              void* d_out, int out_size, void* d_ws, size_t ws_size,
                              hipStream_t stream)
{
    (void)in_sizes; (void)n_in; (void)out_size; (void)ws_size;
    const float* x        = (const float*)d_in[0];
    const float* norm     = (const float*)d_in[1];
    const float* A        = (const float*)d_in[2];
    const float* QinvChol = (const float*)d_in[3];
    const float* Q0invChol= (const float*)d_in[4];
    const float* Wm_in = (const float*)d_in[5];  const float* bm_in = (const float*)d_in[6];
    const float* Wm_h1 = (const float*)d_in[7];  const float* bm_h1 = (const float*)d_in[8];
    const float* Wm_h3 = (const float*)d_in[9];  const float* bm_h3 = (const float*)d_in[10];
    const float* Wm_out= (const float*)d_in[11]; const float* bm_out= (const float*)d_in[12];
    const float* Wc_in = (const float*)d_in[13]; const float* bc_in = (const float*)d_in[14];
    const float* Wc_h1 = (const float*)d_in[15]; const float* bc_h1 = (const float*)d_in[16];
    const float* Wc_h3 = (const float*)d_in[17]; const float* bc_h3 = (const float*)d_in[18];
    const float* Wc_out= (const float*)d_in[19]; const float* bc_out= (const float*)d_in[20];

    float* ws    = (float*)d_ws;
    float* out   = (float*)d_out;
    float* cw    = ws;
    float* Lbuf  = ws + OFF_ACT0;
    float* Cbuf  = ws + OFF_ACT1;
    float* covb  = ws + OFF_AAB;
    float* meanb = ws + OFF_MEANB;
    float* lamMu = ws + OFF_LAMMU;
    float* ib    = ws + OFF_IBV;
    float* logsum = ws + OFF_LOGSUM;

    // 4 f16 activation slots, carved from ACT0/ACT1 regions
    _Float16* s0 = (_Float16*)(ws + OFF_ACT0);
    _Float16* s1 = s0 + 8388608;
    _Float16* s2 = (_Float16*)(ws + OFF_ACT1);
    _Float16* s3 = s2 + 8388608;
    _Float16* xh = (_Float16*)(ws + OFF_XB);

    const long OWmi = OFF_WB;
    const long OWm1 = OWmi + 262144;
    const long OWm3 = OWm1 + 1048576;
    const long OWmo = OWm3 + 1048576;
    const long OWci = OWmo + 32768;
    const long OWc1 = OWci + 262144;
    const long OWc3 = OWc1 + 1048576;
    const long OWco = OWc3 + 1048576;
    #define WH(o) ((_Float16*)(ws + (o)))

    setup_kernel<<<dim3(1), dim3(1024), 0, stream>>>(A, QinvChol, Q0invChol, cw);

    SplitArgs sa;
    sa.seg[0] = { x,      xh,       2097152 };
    sa.seg[1] = { Wm_in,  WH(OWmi), 262144 };
    sa.seg[2] = { Wm_h1,  WH(OWm1), 1048576 };
    sa.seg[3] = { Wm_h3,  WH(OWm3), 1048576 };
    sa.seg[4] = { Wm_out, WH(OWmo), 32768 };
    sa.seg[5] = { Wc_in,  WH(OWci), 262144 };
    sa.seg[6] = { Wc_h1,  WH(OWc1), 1048576 };
    sa.seg[7] = { Wc_h3,  WH(OWc3), 1048576 };
    sa.seg[8] = { Wc_out, WH(OWco), 1048576 };
    split_all<<<dim3(2048, 9), dim3(256), 0, stream>>>(sa);

    const dim3 gM(8, 64, 2), blk(256);
    // L1: x -> s0 (mean h1) / s1 (cov h1)
    mgemm2<<<gM, blk, 0, stream>>>(xh, xh, WH(OWmi), WH(OWci), bm_in, bc_in, s0, s1, 1024, 256);
    // L2: s0 -> s2 / s1 -> s3
    mgemm2<<<gM, blk, 0, stream>>>(s0, s1, WH(OWm1), WH(OWc1), bm_h1, bc_h1, s2, s3, 1024, 1024);
    // L3: s2 -> s0 / s3 -> s1
    mgemm2<<<gM, blk, 0, stream>>>(s2, s3, WH(OWm3), WH(OWc3), bm_h3, bc_h3, s0, s1, 1024, 1024);
    // heads
    mgemm_small<<<dim3(512), dim3(64), 0, stream>>>(s0, WH(OWmo), bm_out, meanb, 1024);
    mgemm_f32<<<dim3(8, 64), blk, 0, stream>>>(s1, WH(OWco), bc_out, covb, 1024, 1024);

    build_blocks_kernel<<<dim3(TT), dim3(256), 0, stream>>>(covb, meanb, lamMu, cw);

    // chol: K=2 -> 4096 blocks; register diet targets 4 waves/SIMD residency
    chol_scan8<<<dim3(TT/2), dim3(64), 0, stream>>>(covb, Lbuf, Cbuf, cw, logsum, 2, 2);
    fwd_solve_kernel<<<dim3(TT/2), dim3(64), 0, stream>>>(Lbuf, Cbuf, lamMu, ib, 2, 6);
    bwd_solve_kernel<<<dim3(TT/2), dim3(64), 0, stream>>>(Lbuf, Cbuf, ib, norm, out, 2, 6);

    finalize_kernel<<<dim3(1), dim3(64), 0, stream>>>(logsum, out);
}

// Round 14
// 392.714 us; speedup vs baseline: 1.1510x; 1.0584x over previous
//
#include <hip/hip_runtime.h>
#include <math.h>

#define TT 8192
#define DZ 32

typedef short bf16x8 __attribute__((ext_vector_type(8)));
typedef _Float16 f16x8 __attribute__((ext_vector_type(8)));
typedef _Float16 f16x4 __attribute__((ext_vector_type(4)));
typedef float f32x4 __attribute__((ext_vector_type(4)));
typedef float f32x16 __attribute__((ext_vector_type(16)));
#define MFMA16F(a,b,c) __builtin_amdgcn_mfma_f32_16x16x32_f16(a,b,c,0,0,0)
#define MFMA32(a,b,c) __builtin_amdgcn_mfma_f32_32x32x16_bf16(a,b,c,0,0,0)

// ---------------- workspace layout (float units) ----------------
#define OFF_QINV   0
#define OFF_Q0INV  1024
#define OFF_AQA    2048
#define OFF_B      3072
#define OFF_P0     4096
#define OFF_PMID   5120
#define OFF_PLAST  6144
#define OFF_LOGSUM 7168
#define OFF_ACT0   8192                     // 2 f16 act slots -> later L (f32, col-major per t)
#define OFF_ACT1   (OFF_ACT0 + 8388608)     // 2 f16 act slots -> later C (f32, X row-major per t)
#define OFF_AAB    (OFF_ACT1 + 8388608)     // cov f32 -> AA in place
#define OFF_XB     (OFF_AAB + 8388608)      // x f16
#define OFF_WB     (OFF_XB + 2097152)       // weights f16
#define OFF_MEANB  (OFF_WB + 5799936)
#define OFF_LAMMU  (OFF_MEANB + 262144)
#define OFF_IBV    (OFF_LAMMU + 262144)

__device__ __forceinline__ unsigned short f2bf(float f) {
    unsigned int u = __float_as_uint(f);
    u += 0x7FFFu + ((u >> 16) & 1u);
    return (unsigned short)(u >> 16);
}
__device__ __forceinline__ float bf2f(unsigned short h) {
    return __uint_as_float(((unsigned int)h) << 16);
}
__device__ __forceinline__ float rlane(float v, int l) {
    return __uint_as_float(__builtin_amdgcn_readlane(__float_as_uint(v), l));
}

// ---------------- fused f32 -> f16 conversion (all tensors, 1 launch) ----------------
struct SplitSeg { const float* src; _Float16* hi; int n; };
struct SplitArgs { SplitSeg seg[9]; };

__global__ __launch_bounds__(256)
void split_all(SplitArgs a)
{
    const SplitSeg sg = a.seg[blockIdx.y];
    const int n4 = sg.n >> 2;
    int i = blockIdx.x * 256 + threadIdx.x;
    if (i >= n4) return;
    float4 v = ((const float4*)sg.src)[i];
    f16x4 hh;
    hh[0] = (_Float16)v.x; hh[1] = (_Float16)v.y;
    hh[2] = (_Float16)v.z; hh[3] = (_Float16)v.w;
    ((f16x4*)sg.hi)[i] = hh;
}

// ---------------- setup: Qinv, Q0inv, AQA, B, priors ----------------
__global__ __launch_bounds__(1024)
void setup_kernel(const float* __restrict__ A, const float* __restrict__ QinvChol,
                  const float* __restrict__ Q0invChol, float* __restrict__ cw)
{
    __shared__ float As[DZ*33], Qc[DZ*33], Q0c[DZ*33], Qi[DZ*33], T1[DZ*33];
    const int tid = threadIdx.x;
    const int i = tid >> 5, j = tid & 31;
    As[i*33+j]  = A[tid];
    Qc[i*33+j]  = QinvChol[tid];
    Q0c[i*33+j] = Q0invChol[tid];
    __syncthreads();
    float qi = 0.f, q0 = 0.f;
    for (int k = 0; k < DZ; ++k) { qi += Qc[i*33+k]*Qc[j*33+k]; q0 += Q0c[i*33+k]*Q0c[j*33+k]; }
    Qi[i*33+j] = qi;
    __syncthreads();
    float t1 = 0.f;
    for (int k = 0; k < DZ; ++k) t1 += Qi[i*33+k]*As[k*33+j];
    T1[i*33+j] = t1;
    __syncthreads();
    float aqa = 0.f, bm = 0.f;
    for (int k = 0; k < DZ; ++k) { aqa += As[k*33+i]*T1[k*33+j]; bm += As[k*33+i]*Qi[k*33+j]; }
    cw[OFF_QINV  + tid] = qi;
    cw[OFF_Q0INV + tid] = q0;
    cw[OFF_AQA   + tid] = aqa;
    cw[OFF_B     + tid] = -bm;
    cw[OFF_P0    + tid] = q0 + aqa;
    cw[OFF_PMID  + tid] = qi + aqa;
    cw[OFF_PLAST + tid] = qi;
    if (tid == 0) cw[OFF_LOGSUM] = 0.f;
}

// ---------------- f16 MFMA GEMM ----------------
__device__ __forceinline__ void stage_tile(const _Float16* src, int rowbase, int Kd,
                                           int k0, _Float16* ldsbase, int w, int lane)
{
#pragma unroll
    for (int inst = 0; inst < 2; ++inst) {
        const int r0  = w * 32 + inst * 16;
        const int row = r0 + (lane >> 2);
        const int g   = (lane & 3) ^ ((row >> 1) & 3);
        const _Float16* gp = src + (size_t)(rowbase + row) * Kd + k0 + g * 8;
        __builtin_amdgcn_global_load_lds(
            (const __attribute__((address_space(1))) void*)gp,
            (__attribute__((address_space(3))) void*)(ldsbase + r0 * 32),
            16, 0, 0);
    }
}

// GEMM body: C = act(A @ W^T + b). OM: 0 f32 out, 1 f16 out.
template<int OM>
__device__ __forceinline__ void mgemm_body(const _Float16* Ah, const _Float16* Wh,
                                           const float* bias, float* outF,
                                           _Float16* outH, int N, int Kd, int relu,
                                           int bn, int bm, _Float16 (*lds)[2][4096])
{
    const int tid = threadIdx.x;
    const int lane = tid & 63, w = tid >> 6;
    const int wm = w >> 1, wn = w & 1;
    const int ln15 = lane & 15, g4 = lane >> 4;

    f32x4 acc[4][4];
#pragma unroll
    for (int i = 0; i < 4; ++i)
#pragma unroll
        for (int j = 0; j < 4; ++j) acc[i][j] = f32x4{0.f,0.f,0.f,0.f};

    const int nt = Kd >> 5;
    stage_tile(Ah, bm*128, Kd, 0, &lds[0][0][0], w, lane);
    stage_tile(Wh, bn*128, Kd, 0, &lds[0][1][0], w, lane);
    __syncthreads();

    int cur = 0;
    for (int t = 0; t < nt; ++t) {
        if (t + 1 < nt) {
            const int k0 = (t + 1) << 5;
            stage_tile(Ah, bm*128, Kd, k0, &lds[cur^1][0][0], w, lane);
            stage_tile(Wh, bn*128, Kd, k0, &lds[cur^1][1][0], w, lane);
        }
        f16x8 fa[4], fwh[4];
#pragma unroll
        for (int fm = 0; fm < 4; ++fm) {
            const int lr = wm*64 + fm*16 + ln15;
            const int off = lr*32 + ((g4 ^ ((lr >> 1) & 3)) << 3);
            fa[fm]  = *(const f16x8*)(&lds[cur][0][0] + off);
        }
#pragma unroll
        for (int fn = 0; fn < 4; ++fn) {
            const int lr = wn*64 + fn*16 + ln15;
            const int off = lr*32 + ((g4 ^ ((lr >> 1) & 3)) << 3);
            fwh[fn] = *(const f16x8*)(&lds[cur][1][0] + off);
        }
#pragma unroll
        for (int fm = 0; fm < 4; ++fm)
#pragma unroll
            for (int fn = 0; fn < 4; ++fn)
                acc[fm][fn] = MFMA16F(fa[fm], fwh[fn], acc[fm][fn]);
        __syncthreads();
        cur ^= 1;
    }

    // epilogue: C/D layout col=lane&15, row=(lane>>4)*4+q  [m89-verified]
#pragma unroll
    for (int fm = 0; fm < 4; ++fm)
#pragma unroll
        for (int fn = 0; fn < 4; ++fn) {
            const int col = bn*128 + wn*64 + fn*16 + ln15;
            const float bv = bias[col];
#pragma unroll
            for (int q = 0; q < 4; ++q) {
                const int row = bm*128 + wm*64 + fm*16 + g4*4 + q;
                float v = acc[fm][fn][q] + bv;
                if (relu) v = fmaxf(v, 0.f);
                if (OM == 0) outF[(size_t)row * N + col] = v;
                else         outH[(size_t)row * N + col] = (_Float16)v;
            }
        }
}

// single-chain GEMM (final cov layer, f32 out)
__global__ __launch_bounds__(256)
void mgemm_f32(const _Float16* __restrict__ Ah, const _Float16* __restrict__ Wh,
               const float* __restrict__ bias, float* __restrict__ outF,
               int N, int Kd)
{
    __shared__ _Float16 lds[2][2][4096];
    mgemm_body<0>(Ah, Wh, bias, outF, nullptr, N, Kd, 0, blockIdx.x, blockIdx.y, lds);
}

// merged mean/cov GEMM: blockIdx.z selects chain (both f16 out, relu)
__global__ __launch_bounds__(256)
void mgemm2(const _Float16* __restrict__ A0, const _Float16* __restrict__ A1,
            const _Float16* __restrict__ W0, const _Float16* __restrict__ W1,
            const float* __restrict__ b0, const float* __restrict__ b1,
            _Float16* __restrict__ o0, _Float16* __restrict__ o1,
            int N, int Kd)
{
    __shared__ _Float16 lds[2][2][4096];
    const int z = blockIdx.z;
    const _Float16* Ah = z ? A1 : A0;
    const _Float16* Wh = z ? W1 : W0;
    const float* bias  = z ? b1 : b0;
    _Float16* outH     = z ? o1 : o0;
    mgemm_body<1>(Ah, Wh, bias, nullptr, outH, N, Kd, 1, blockIdx.x, blockIdx.y, lds);
}

// ---------------- small GEMM (N=32): mean = h3 @ Wm_out^T + b ----------------
__global__ __launch_bounds__(64)
void mgemm_small(const _Float16* __restrict__ Ah, const _Float16* __restrict__ Wh,
                 const float* __restrict__ bias, float* __restrict__ out, int Kd)
{
    const int lane = threadIdx.x;
    const int rm = blockIdx.x * 16;
    const int ln15 = lane & 15, g = lane >> 4;
    const int row = rm + ln15;
    f32x4 acc0 = {0.f,0.f,0.f,0.f}, acc1 = {0.f,0.f,0.f,0.f};
    for (int k0 = 0; k0 < Kd; k0 += 32) {
        const int k = k0 + g*8;
        f16x8 a  = *(const f16x8*)(Ah + (size_t)row*Kd + k);
        f16x8 w0h = *(const f16x8*)(Wh + (size_t)ln15*Kd + k);
        f16x8 w1h = *(const f16x8*)(Wh + (size_t)(16+ln15)*Kd + k);
        acc0 = MFMA16F(a, w0h, acc0);
        acc1 = MFMA16F(a, w1h, acc1);
    }
#pragma unroll
    for (int q = 0; q < 4; ++q) {
        const int r = rm + g*4 + q;
        out[r*DZ + ln15]      = acc0[q] + bias[ln15];
        out[r*DZ + 16 + ln15] = acc1[q] + bias[16 + ln15];
    }
}

// ---------------- build Lam, AA (in place over cov), lamMu ----------------
__global__ __launch_bounds__(256)
void build_blocks_kernel(float* __restrict__ cov, const float* __restrict__ mean,
                         float* __restrict__ lamMu, const float* __restrict__ cw)
{
    const int t = blockIdx.x, tid = threadIdx.x;
    __shared__ float R[DZ*33];
    __shared__ float Lam[DZ*33];
    __shared__ float mn[DZ];
    float* blk = cov + (size_t)t * 1024;
    {
        float4 v = ((const float4*)blk)[tid];
        const int base = tid * 4;
        const int row = base >> 5, col = base & 31;
        R[row*33 + col + 0] = v.x; R[row*33 + col + 1] = v.y;
        R[row*33 + col + 2] = v.z; R[row*33 + col + 3] = v.w;
    }
    if (tid < DZ) mn[tid] = mean[t*DZ + tid];
    __syncthreads();
    const float* P = cw + (t == 0 ? OFF_P0 : (t == TT-1 ? OFF_PLAST : OFF_PMID));
#pragma unroll
    for (int q = 0; q < 4; ++q) {
        const int idx = tid + 256*q;
        const int i = idx >> 5, j = idx & 31;
        float s = 0.f;
#pragma unroll
        for (int k = 0; k < DZ; ++k) s += R[i*33+k] * R[j*33+k];
        Lam[i*33+j] = s;
        blk[idx] = s + P[idx];
    }
    __syncthreads();
    if (tid < DZ) {
        float s = 0.f;
#pragma unroll
        for (int k = 0; k < DZ; ++k) s += Lam[tid*33+k] * mn[k];
        lamMu[t*DZ + tid] = s;
    }
}

// ---------------- chol scan v8 (unchanged kernel): K=4/W=2 work-reduction ----------
// r13 ledger: wall ~ wave-steps / VALUBusy. With VGPR=64, K=4 (12288 ws @ 2 w/SIMD)
// beats K=2 (16384 ws @ 4 w/SIMD): 12288/0.62 < 16384/0.68.
__device__ __forceinline__ unsigned short f2bf_c(float f) { return f2bf(f); }

#define CHOL_STEP2(OWNED)                                                         \
    {                                                                             \
        const float* at = AA + (size_t)t * 1024;                                  \
        _Pragma("unroll")                                                         \
        for (int i = 0; i < 32; ++i) s[i] = at[i*32 + c];                         \
        const bool doX = (t > t0);                                                \
        if (doX) {                                                                \
            _Pragma("unroll")                                                     \
            for (int i = 0; i < 32; ++i) u[i] = Bs[i*32 + c];                     \
            _Pragma("unroll")                                                     \
            for (int r = 0; r < 32; ++r) {                                        \
                float x = u[r] * rlane(invd_own, r);                              \
                u[r] = x;                                                         \
                _Pragma("unroll")                                                 \
                for (int i = r+1; i < 32; ++i)                                    \
                    u[i] = fmaf(-rlane(Lcol[i], r), x, u[i]);                     \
            }                                                                     \
            if (OWNED) {                                                          \
                float* ct = Cg + (size_t)t*1024;                                  \
                _Pragma("unroll")                                                 \
                for (int rr = 0; rr < 16; ++rr) {                                 \
                    float val = h ? u[16+rr] : u[rr];                             \
                    ct[(h*16+rr)*32 + c] = val;                                   \
                }                                                                 \
            }                                                                     \
            float f0[8], f1[8];                                                   \
            _Pragma("unroll")                                                     \
            for (int j = 0; j < 8; ++j) {                                         \
                f0[j] = h ? u[8+j]  : u[j];                                       \
                f1[j] = h ? u[24+j] : u[16+j];                                    \
            }                                                                     \
            bf16x8 A0h, A0l, A1h, A1l;                                            \
            _Pragma("unroll")                                                     \
            for (int j = 0; j < 8; ++j) {                                         \
                unsigned short hh0 = f2bf_c(f0[j]);                               \
                A0h[j] = (short)hh0; A0l[j] = (short)f2bf_c(f0[j] - bf2f(hh0));   \
                unsigned short hh1 = f2bf_c(f1[j]);                               \
                A1h[j] = (short)hh1; A1l[j] = (short)f2bf_c(f1[j] - bf2f(hh1));   \
            }                                                                     \
            f32x16 d;                                                             \
            _Pragma("unroll")                                                     \
            for (int q = 0; q < 16; ++q) d[q] = 0.f;                              \
            d = MFMA32(A0h, A0h, d);                                              \
            d = MFMA32(A0h, A0l, d);                                              \
            d = MFMA32(A0l, A0h, d);                                              \
            d = MFMA32(A1h, A1h, d);                                              \
            d = MFMA32(A1h, A1l, d);                                              \
            d = MFMA32(A1l, A1h, d);                                              \
            float dsw[16];                                                        \
            _Pragma("unroll")                                                     \
            for (int q = 0; q < 16; ++q) dsw[q] = __shfl_xor(d[q], 32);           \
            _Pragma("unroll")                                                     \
            for (int i = 0; i < 32; ++i) {                                        \
                const int q  = (i & 3) + ((i >> 3) << 2);                         \
                const int hh = (i >> 2) & 1;                                      \
                s[i] -= (h == hh) ? d[q] : dsw[q];                                \
            }                                                                     \
        }                                                                         \
        float pivk = 1.f;                                                         \
        _Pragma("unroll")                                                         \
        for (int j = 0; j < 32; ++j) {                                            \
            float sjj = rlane(s[j], j);                                           \
            float inv = __builtin_amdgcn_rsqf(sjj);                               \
            pivk = (c == j) ? sjj : pivk;                                         \
            float inv2 = inv * inv;                                               \
            float ljc = (c > j) ? s[j] * inv2 : 0.f;                              \
            invd_own = (c == j) ? inv : invd_own;                                 \
            _Pragma("unroll")                                                     \
            for (int i = j; i < 32; ++i) s[i] = fmaf(-rlane(s[i], j), ljc, s[i]); \
        }                                                                         \
        if (OWNED) logacc += __logf(pivk);                                        \
        _Pragma("unroll")                                                         \
        for (int i = 0; i < 32; ++i) Lcol[i] = s[i] * invd_own;                   \
        if (OWNED) {                                                              \
            float* lt = Lg + (size_t)t*1024 + c*32 + h*16;                        \
            _Pragma("unroll")                                                     \
            for (int q = 0; q < 4; ++q) {                                         \
                float4 v4 = make_float4(h ? Lcol[16+4*q]   : Lcol[4*q],           \
                                        h ? Lcol[16+4*q+1] : Lcol[4*q+1],         \
                                        h ? Lcol[16+4*q+2] : Lcol[4*q+2],         \
                                        h ? Lcol[16+4*q+3] : Lcol[4*q+3]);        \
                *(float4*)(lt + 4*q) = v4;                                        \
            }                                                                     \
        }                                                                         \
    }

__global__ __launch_bounds__(64)
void chol_scan8(const float* __restrict__ AA, float* __restrict__ Lg,
                float* __restrict__ Cg, const float* __restrict__ cw,
                float* __restrict__ logsum, int K, int W)
{
    const int lane = threadIdx.x;
    const int c = lane & 31;
    const int h = lane >> 5;
    const int own0 = blockIdx.x * K;
    const int own1 = min(TT, own0 + K);
    const int t0 = max(0, own0 - W);

    __shared__ float Bs[1024];
#pragma unroll
    for (int i = 0; i < 16; ++i) Bs[i*64 + lane] = cw[OFF_B + i*64 + lane];
    __syncthreads();

    float Lcol[32], s[32], u[32];
    float invd_own = 0.f, logacc = 0.f;

    for (int t = t0; t < own0; ++t) CHOL_STEP2(false)
    for (int t = own0; t < own1; ++t) CHOL_STEP2(true)

    // lane c holds sum over owned steps of log(pivot_c); butterfly within 32
#pragma unroll
    for (int sft = 16; sft > 0; sft >>= 1) logacc += __shfl_xor(logacc, sft);
    if (lane == 0) atomicAdd(logsum, logacc * 0.5f);
}

// ---------------- chunked forward bidiagonal solve (L col-major, C = X row-major) -------
// Solves are HBM-BW-bound: bytes = blocks*(K+W)*8KB. K=8/W=4 -> 98 MB (was 268 at K=2/W=6).
__global__ __launch_bounds__(64)
void fwd_solve_kernel(const float* __restrict__ Lg, const float* __restrict__ Cg,
                      const float* __restrict__ bv, float* __restrict__ xout,
                      int K, int W)
{
    const int lane = threadIdx.x;
    const int r = lane & 31, h = lane >> 5;
    const int own0 = blockIdx.x * K;
    const int own1 = min(TT, own0 + K);
    const int t0 = max(0, own0 - W);
    float xprev = 0.f;
    for (int t = t0; t < own1; ++t) {
        const float* lt = Lg + (size_t)t * 1024;
        float Lr[32];
#pragma unroll
        for (int j = 0; j < DZ; ++j) Lr[j] = lt[j*32 + r];
        const float inv = __builtin_amdgcn_rcpf(Lr[r]);
        float v = bv[t*DZ + r];
        if (t > t0) {
            const float* ct = Cg + (size_t)t * 1024;
            float Cr[32];
#pragma unroll
            for (int cc = 0; cc < DZ; ++cc) Cr[cc] = ct[cc*32 + r];
#pragma unroll
            for (int cc = 0; cc < DZ; ++cc) v = fmaf(-Cr[cc], __shfl(xprev, cc), v);
        }
        float xv = 0.f;
#pragma unroll
        for (int rr = 0; rr < DZ; ++rr) {
            float cand = v * inv;
            float xb = __shfl(cand, rr);
            if (r == rr) xv = cand;
            if (r > rr) v = fmaf(-Lr[rr], xb, v);
        }
        xprev = xv;
        if (t >= own0 && h == 0) xout[t*DZ + r] = xv;
    }
}

// ---------------- chunked backward solve (two RHS) + sample -----------------------------
__global__ __launch_bounds__(64)
void bwd_solve_kernel(const float* __restrict__ Lg, const float* __restrict__ Cg,
                      const float* __restrict__ b1, const float* __restrict__ b2,
                      float* __restrict__ outSample, int K, int W)
{
    const int lane = threadIdx.x;
    const int k = lane & 31, h = lane >> 5;
    const int own0 = blockIdx.x * K;
    const int own1 = min(TT, own0 + K);
    const int tS = min(TT - 1, own1 - 1 + W);
    float x1p = 0.f, x2p = 0.f;
    for (int t = tS; t >= own0; --t) {
        const float* lt = Lg + (size_t)t * 1024;
        float Lc[32];
#pragma unroll
        for (int q = 0; q < 8; ++q) {
            float4 v4 = *(const float4*)(lt + k*32 + 4*q);
            Lc[4*q] = v4.x; Lc[4*q+1] = v4.y; Lc[4*q+2] = v4.z; Lc[4*q+3] = v4.w;
        }
        const float inv = __builtin_amdgcn_rcpf(Lc[k]);
        float v1 = b1[t*DZ + k], v2 = b2[t*DZ + k];
        if (t < tS) {
            const float* ct = Cg + (size_t)(t+1) * 1024;
            float Cc[32];
#pragma unroll
            for (int q = 0; q < 8; ++q) {
                float4 w4 = *(const float4*)(ct + k*32 + 4*q);
                Cc[4*q] = w4.x; Cc[4*q+1] = w4.y; Cc[4*q+2] = w4.z; Cc[4*q+3] = w4.w;
            }
#pragma unroll
            for (int cc = 0; cc < DZ; ++cc) {
                float a1 = __shfl(x1p, cc), a2 = __shfl(x2p, cc);
                v1 = fmaf(-Cc[cc], a1, v1); v2 = fmaf(-Cc[cc], a2, v2);
            }
        }
        float x1 = 0.f, x2 = 0.f;
#pragma unroll
        for (int rr = DZ-1; rr >= 0; --rr) {
            float c1 = v1 * inv, c2 = v2 * inv;
            float xb1 = __shfl(c1, rr), xb2 = __shfl(c2, rr);
            if (k == rr) { x1 = c1; x2 = c2; }
            if (k < rr) { v1 = fmaf(-Lc[rr], xb1, v1); v2 = fmaf(-Lc[rr], xb2, v2); }
        }
        x1p = x1; x2p = x2;
        if (t >= own0 && h == 0) outSample[t*DZ + k] = x1 + x2;
    }
}

// ---------------- entropy ----------------
__global__ void finalize_kernel(const float* __restrict__ logsum, float* __restrict__ out)
{
    if (threadIdx.x == 0) {
        out[TT*DZ] = (logsum[0] - 2270.3016531274763f) / 409600.0f;
    }
}

// ---------------- launch ----------------
extern "C" void kernel_launch(void* const* d_in, const int* in_sizes, int n_in,
                              void* d_out, int out_size, void* d_ws, size_t ws_size,
                              hipStream_t stream)
{
    (void)in_sizes; (void)n_in; (void)out_size; (void)ws_size;
    const float* x        = (const float*)d_in[0];
    const float* norm     = (const float*)d_in[1];
    const float* A        = (const float*)d_in[2];
    const float* QinvChol = (const float*)d_in[3];
    const float* Q0invChol= (const float*)d_in[4];
    const float* Wm_in = (const float*)d_in[5];  const float* bm_in = (const float*)d_in[6];
    const float* Wm_h1 = (const float*)d_in[7];  const float* bm_h1 = (const float*)d_in[8];
    const float* Wm_h3 = (const float*)d_in[9];  const float* bm_h3 = (const float*)d_in[10];
    const float* Wm_out= (const float*)d_in[11]; const float* bm_out= (const float*)d_in[12];
    const float* Wc_in = (const float*)d_in[13]; const float* bc_in = (const float*)d_in[14];
    const float* Wc_h1 = (const float*)d_in[15]; const float* bc_h1 = (const float*)d_in[16];
    const float* Wc_h3 = (const float*)d_in[17]; const float* bc_h3 = (const float*)d_in[18];
    const float* Wc_out= (const float*)d_in[19]; const float* bc_out= (const float*)d_in[20];

    float* ws    = (float*)d_ws;
    float* out   = (float*)d_out;
    float* cw    = ws;
    float* Lbuf  = ws + OFF_ACT0;
    float* Cbuf  = ws + OFF_ACT1;
    float* covb  = ws + OFF_AAB;
    float* meanb = ws + OFF_MEANB;
    float* lamMu = ws + OFF_LAMMU;
    float* ib    = ws + OFF_IBV;
    float* logsum = ws + OFF_LOGSUM;

    // 4 f16 activation slots, carved from ACT0/ACT1 regions
    _Float16* s0 = (_Float16*)(ws + OFF_ACT0);
    _Float16* s1 = s0 + 8388608;
    _Float16* s2 = (_Float16*)(ws + OFF_ACT1);
    _Float16* s3 = s2 + 8388608;
    _Float16* xh = (_Float16*)(ws + OFF_XB);

    const long OWmi = OFF_WB;
    const long OWm1 = OWmi + 262144;
    const long OWm3 = OWm1 + 1048576;
    const long OWmo = OWm3 + 1048576;
    const long OWci = OWmo + 32768;
    const long OWc1 = OWci + 262144;
    const long OWc3 = OWc1 + 1048576;
    const long OWco = OWc3 + 1048576;
    #define WH(o) ((_Float16*)(ws + (o)))

    setup_kernel<<<dim3(1), dim3(1024), 0, stream>>>(A, QinvChol, Q0invChol, cw);

    SplitArgs sa;
    sa.seg[0] = { x,      xh,       2097152 };
    sa.seg[1] = { Wm_in,  WH(OWmi), 262144 };
    sa.seg[2] = { Wm_h1,  WH(OWm1), 1048576 };
    sa.seg[3] = { Wm_h3,  WH(OWm3), 1048576 };
    sa.seg[4] = { Wm_out, WH(OWmo), 32768 };
    sa.seg[5] = { Wc_in,  WH(OWci), 262144 };
    sa.seg[6] = { Wc_h1,  WH(OWc1), 1048576 };
    sa.seg[7] = { Wc_h3,  WH(OWc3), 1048576 };
    sa.seg[8] = { Wc_out, WH(OWco), 1048576 };
    split_all<<<dim3(2048, 9), dim3(256), 0, stream>>>(sa);

    const dim3 gM(8, 64, 2), blk(256);
    // L1: x -> s0 (mean h1) / s1 (cov h1)
    mgemm2<<<gM, blk, 0, stream>>>(xh, xh, WH(OWmi), WH(OWci), bm_in, bc_in, s0, s1, 1024, 256);
    // L2: s0 -> s2 / s1 -> s3
    mgemm2<<<gM, blk, 0, stream>>>(s0, s1, WH(OWm1), WH(OWc1), bm_h1, bc_h1, s2, s3, 1024, 1024);
    // L3: s2 -> s0 / s3 -> s1
    mgemm2<<<gM, blk, 0, stream>>>(s2, s3, WH(OWm3), WH(OWc3), bm_h3, bc_h3, s0, s1, 1024, 1024);
    // heads
    mgemm_small<<<dim3(512), dim3(64), 0, stream>>>(s0, WH(OWmo), bm_out, meanb, 1024);
    mgemm_f32<<<dim3(8, 64), blk, 0, stream>>>(s1, WH(OWco), bc_out, covb, 1024, 1024);

    build_blocks_kernel<<<dim3(TT), dim3(256), 0, stream>>>(covb, meanb, lamMu, cw);

    // chol: K=4 -> 2048 blocks (work reduction; VGPR=64 kernel unchanged)
    chol_scan8<<<dim3(TT/4), dim3(64), 0, stream>>>(covb, Lbuf, Cbuf, cw, logsum, 4, 2);
    // solves: K=8/W=4 -> 98 MB HBM each (BW-bound fix)
    fwd_solve_kernel<<<dim3(TT/8), dim3(64), 0, stream>>>(Lbuf, Cbuf, lamMu, ib, 8, 4);
    bwd_solve_kernel<<<dim3(TT/8), dim3(64), 0, stream>>>(Lbuf, Cbuf, ib, norm, out, 8, 4);

    finalize_kernel<<<dim3(1), dim3(64), 0, stream>>>(logsum, out);
}

// Round 15
// 373.805 us; speedup vs baseline: 1.2092x; 1.0506x over previous
//
#include <hip/hip_runtime.h>
#include <math.h>

#define TT 8192
#define DZ 32

typedef short bf16x8 __attribute__((ext_vector_type(8)));
typedef _Float16 f16x8 __attribute__((ext_vector_type(8)));
typedef _Float16 f16x4 __attribute__((ext_vector_type(4)));
typedef float f32x4 __attribute__((ext_vector_type(4)));
typedef float f32x16 __attribute__((ext_vector_type(16)));
#define MFMA16F(a,b,c) __builtin_amdgcn_mfma_f32_16x16x32_f16(a,b,c,0,0,0)
#define MFMA32(a,b,c) __builtin_amdgcn_mfma_f32_32x32x16_bf16(a,b,c,0,0,0)

// ---------------- workspace layout (float units) ----------------
#define OFF_QINV   0
#define OFF_Q0INV  1024
#define OFF_AQA    2048
#define OFF_B      3072
#define OFF_P0     4096
#define OFF_PMID   5120
#define OFF_PLAST  6144
#define OFF_LOGSUM 7168
#define OFF_ACT0   8192                     // 2 f16 act slots -> later L (f32, col-major per t)
#define OFF_ACT1   (OFF_ACT0 + 8388608)     // 2 f16 act slots -> later C (f32, X row-major per t)
#define OFF_AAB    (OFF_ACT1 + 8388608)     // cov f32 -> AA in place
#define OFF_XB     (OFF_AAB + 8388608)      // x f16
#define OFF_WB     (OFF_XB + 2097152)       // weights f16
#define OFF_MEANB  (OFF_WB + 5799936)
#define OFF_LAMMU  (OFF_MEANB + 262144)
#define OFF_IBV    (OFF_LAMMU + 262144)

__device__ __forceinline__ unsigned short f2bf(float f) {
    unsigned int u = __float_as_uint(f);
    u += 0x7FFFu + ((u >> 16) & 1u);
    return (unsigned short)(u >> 16);
}
__device__ __forceinline__ float bf2f(unsigned short h) {
    return __uint_as_float(((unsigned int)h) << 16);
}
__device__ __forceinline__ float rlane(float v, int l) {
    return __uint_as_float(__builtin_amdgcn_readlane(__float_as_uint(v), l));
}

// ---------------- fused f32 -> f16 conversion (all tensors, 1 launch) ----------------
struct SplitSeg { const float* src; _Float16* hi; int n; };
struct SplitArgs { SplitSeg seg[9]; };

__global__ __launch_bounds__(256)
void split_all(SplitArgs a)
{
    const SplitSeg sg = a.seg[blockIdx.y];
    const int n4 = sg.n >> 2;
    int i = blockIdx.x * 256 + threadIdx.x;
    if (i >= n4) return;
    float4 v = ((const float4*)sg.src)[i];
    f16x4 hh;
    hh[0] = (_Float16)v.x; hh[1] = (_Float16)v.y;
    hh[2] = (_Float16)v.z; hh[3] = (_Float16)v.w;
    ((f16x4*)sg.hi)[i] = hh;
}

// ---------------- setup: Qinv, Q0inv, AQA, B, priors ----------------
__global__ __launch_bounds__(1024)
void setup_kernel(const float* __restrict__ A, const float* __restrict__ QinvChol,
                  const float* __restrict__ Q0invChol, float* __restrict__ cw)
{
    __shared__ float As[DZ*33], Qc[DZ*33], Q0c[DZ*33], Qi[DZ*33], T1[DZ*33];
    const int tid = threadIdx.x;
    const int i = tid >> 5, j = tid & 31;
    As[i*33+j]  = A[tid];
    Qc[i*33+j]  = QinvChol[tid];
    Q0c[i*33+j] = Q0invChol[tid];
    __syncthreads();
    float qi = 0.f, q0 = 0.f;
    for (int k = 0; k < DZ; ++k) { qi += Qc[i*33+k]*Qc[j*33+k]; q0 += Q0c[i*33+k]*Q0c[j*33+k]; }
    Qi[i*33+j] = qi;
    __syncthreads();
    float t1 = 0.f;
    for (int k = 0; k < DZ; ++k) t1 += Qi[i*33+k]*As[k*33+j];
    T1[i*33+j] = t1;
    __syncthreads();
    float aqa = 0.f, bm = 0.f;
    for (int k = 0; k < DZ; ++k) { aqa += As[k*33+i]*T1[k*33+j]; bm += As[k*33+i]*Qi[k*33+j]; }
    cw[OFF_QINV  + tid] = qi;
    cw[OFF_Q0INV + tid] = q0;
    cw[OFF_AQA   + tid] = aqa;
    cw[OFF_B     + tid] = -bm;
    cw[OFF_P0    + tid] = q0 + aqa;
    cw[OFF_PMID  + tid] = qi + aqa;
    cw[OFF_PLAST + tid] = qi;
    if (tid == 0) cw[OFF_LOGSUM] = 0.f;
}

// ---------------- f16 MFMA GEMM ----------------
__device__ __forceinline__ void stage_tile(const _Float16* src, int rowbase, int Kd,
                                           int k0, _Float16* ldsbase, int w, int lane)
{
#pragma unroll
    for (int inst = 0; inst < 2; ++inst) {
        const int r0  = w * 32 + inst * 16;
        const int row = r0 + (lane >> 2);
        const int g   = (lane & 3) ^ ((row >> 1) & 3);
        const _Float16* gp = src + (size_t)(rowbase + row) * Kd + k0 + g * 8;
        __builtin_amdgcn_global_load_lds(
            (const __attribute__((address_space(1))) void*)gp,
            (__attribute__((address_space(3))) void*)(ldsbase + r0 * 32),
            16, 0, 0);
    }
}

// GEMM body: C = act(A @ W^T + b). OM: 0 f32 out, 1 f16 out.
template<int OM>
__device__ __forceinline__ void mgemm_body(const _Float16* Ah, const _Float16* Wh,
                                           const float* bias, float* outF,
                                           _Float16* outH, int N, int Kd, int relu,
                                           int bn, int bm, _Float16 (*lds)[2][4096])
{
    const int tid = threadIdx.x;
    const int lane = tid & 63, w = tid >> 6;
    const int wm = w >> 1, wn = w & 1;
    const int ln15 = lane & 15, g4 = lane >> 4;

    f32x4 acc[4][4];
#pragma unroll
    for (int i = 0; i < 4; ++i)
#pragma unroll
        for (int j = 0; j < 4; ++j) acc[i][j] = f32x4{0.f,0.f,0.f,0.f};

    const int nt = Kd >> 5;
    stage_tile(Ah, bm*128, Kd, 0, &lds[0][0][0], w, lane);
    stage_tile(Wh, bn*128, Kd, 0, &lds[0][1][0], w, lane);
    __syncthreads();

    int cur = 0;
    for (int t = 0; t < nt; ++t) {
        if (t + 1 < nt) {
            const int k0 = (t + 1) << 5;
            stage_tile(Ah, bm*128, Kd, k0, &lds[cur^1][0][0], w, lane);
            stage_tile(Wh, bn*128, Kd, k0, &lds[cur^1][1][0], w, lane);
        }
        f16x8 fa[4], fwh[4];
#pragma unroll
        for (int fm = 0; fm < 4; ++fm) {
            const int lr = wm*64 + fm*16 + ln15;
            const int off = lr*32 + ((g4 ^ ((lr >> 1) & 3)) << 3);
            fa[fm]  = *(const f16x8*)(&lds[cur][0][0] + off);
        }
#pragma unroll
        for (int fn = 0; fn < 4; ++fn) {
            const int lr = wn*64 + fn*16 + ln15;
            const int off = lr*32 + ((g4 ^ ((lr >> 1) & 3)) << 3);
            fwh[fn] = *(const f16x8*)(&lds[cur][1][0] + off);
        }
#pragma unroll
        for (int fm = 0; fm < 4; ++fm)
#pragma unroll
            for (int fn = 0; fn < 4; ++fn)
                acc[fm][fn] = MFMA16F(fa[fm], fwh[fn], acc[fm][fn]);
        __syncthreads();
        cur ^= 1;
    }

    // epilogue: C/D layout col=lane&15, row=(lane>>4)*4+q  [m89-verified]
#pragma unroll
    for (int fm = 0; fm < 4; ++fm)
#pragma unroll
        for (int fn = 0; fn < 4; ++fn) {
            const int col = bn*128 + wn*64 + fn*16 + ln15;
            const float bv = bias[col];
#pragma unroll
            for (int q = 0; q < 4; ++q) {
                const int row = bm*128 + wm*64 + fm*16 + g4*4 + q;
                float v = acc[fm][fn][q] + bv;
                if (relu) v = fmaxf(v, 0.f);
                if (OM == 0) outF[(size_t)row * N + col] = v;
                else         outH[(size_t)row * N + col] = (_Float16)v;
            }
        }
}

// merged mean/cov GEMM: blockIdx.z selects chain (both f16 out, relu)
__global__ __launch_bounds__(256)
void mgemm2(const _Float16* __restrict__ A0, const _Float16* __restrict__ A1,
            const _Float16* __restrict__ W0, const _Float16* __restrict__ W1,
            const float* __restrict__ b0, const float* __restrict__ b1,
            _Float16* __restrict__ o0, _Float16* __restrict__ o1,
            int N, int Kd)
{
    __shared__ _Float16 lds[2][2][4096];
    const int z = blockIdx.z;
    const _Float16* Ah = z ? A1 : A0;
    const _Float16* Wh = z ? W1 : W0;
    const float* bias  = z ? b1 : b0;
    _Float16* outH     = z ? o1 : o0;
    mgemm_body<1>(Ah, Wh, bias, nullptr, outH, N, Kd, 1, blockIdx.x, blockIdx.y, lds);
}

// combined heads: x<8 -> cov head (f32 GEMM tile); x==8 -> mean head (N=32) for 128 rows
__global__ __launch_bounds__(256)
void mgemm_heads(const _Float16* __restrict__ Ac, const _Float16* __restrict__ Wc,
                 const float* __restrict__ bc, float* __restrict__ outC,
                 const _Float16* __restrict__ Am, const _Float16* __restrict__ Wm,
                 const float* __restrict__ bm, float* __restrict__ outM,
                 int N, int Kd)
{
    __shared__ _Float16 lds[2][2][4096];
    if (blockIdx.x < 8) {
        mgemm_body<0>(Ac, Wc, bc, outC, nullptr, N, Kd, 0, blockIdx.x, blockIdx.y, lds);
    } else {
        const int tid = threadIdx.x;
        const int grp = tid >> 6, lane = tid & 63;
        const int ln15 = lane & 15, g = lane >> 4;
#pragma unroll
        for (int u = 0; u < 2; ++u) {
            const int rm = blockIdx.y * 128 + grp * 32 + u * 16;
            const int row = rm + ln15;
            f32x4 acc0 = {0.f,0.f,0.f,0.f}, acc1 = {0.f,0.f,0.f,0.f};
            for (int k0 = 0; k0 < Kd; k0 += 32) {
                const int k = k0 + g*8;
                f16x8 a  = *(const f16x8*)(Am + (size_t)row*Kd + k);
                f16x8 w0 = *(const f16x8*)(Wm + (size_t)ln15*Kd + k);
                f16x8 w1 = *(const f16x8*)(Wm + (size_t)(16+ln15)*Kd + k);
                acc0 = MFMA16F(a, w0, acc0);
                acc1 = MFMA16F(a, w1, acc1);
            }
#pragma unroll
            for (int q = 0; q < 4; ++q) {
                const int r = rm + g*4 + q;
                outM[r*DZ + ln15]      = acc0[q] + bm[ln15];
                outM[r*DZ + 16 + ln15] = acc1[q] + bm[16 + ln15];
            }
        }
    }
}

// ---------------- build Lam, AA (in place over cov), lamMu ----------------
__global__ __launch_bounds__(256)
void build_blocks_kernel(float* __restrict__ cov, const float* __restrict__ mean,
                         float* __restrict__ lamMu, const float* __restrict__ cw)
{
    const int t = blockIdx.x, tid = threadIdx.x;
    __shared__ float R[DZ*33];
    __shared__ float Lam[DZ*33];
    __shared__ float mn[DZ];
    float* blk = cov + (size_t)t * 1024;
    {
        float4 v = ((const float4*)blk)[tid];
        const int base = tid * 4;
        const int row = base >> 5, col = base & 31;
        R[row*33 + col + 0] = v.x; R[row*33 + col + 1] = v.y;
        R[row*33 + col + 2] = v.z; R[row*33 + col + 3] = v.w;
    }
    if (tid < DZ) mn[tid] = mean[t*DZ + tid];
    __syncthreads();
    const float* P = cw + (t == 0 ? OFF_P0 : (t == TT-1 ? OFF_PLAST : OFF_PMID));
#pragma unroll
    for (int q = 0; q < 4; ++q) {
        const int idx = tid + 256*q;
        const int i = idx >> 5, j = idx & 31;
        float s = 0.f;
#pragma unroll
        for (int k = 0; k < DZ; ++k) s += R[i*33+k] * R[j*33+k];
        Lam[i*33+j] = s;
        blk[idx] = s + P[idx];
    }
    __syncthreads();
    if (tid < DZ) {
        float s = 0.f;
#pragma unroll
        for (int k = 0; k < DZ; ++k) s += Lam[tid*33+k] * mn[k];
        lamMu[t*DZ + tid] = s;
    }
}

// ---------------- chol scan v8: K=2/W=1 (contraction rho ~ 2e-3/step) ----------
__device__ __forceinline__ unsigned short f2bf_c(float f) { return f2bf(f); }

#define CHOL_STEP2(OWNED)                                                         \
    {                                                                             \
        const float* at = AA + (size_t)t * 1024;                                  \
        _Pragma("unroll")                                                         \
        for (int i = 0; i < 32; ++i) s[i] = at[i*32 + c];                         \
        const bool doX = (t > t0);                                                \
        if (doX) {                                                                \
            _Pragma("unroll")                                                     \
            for (int i = 0; i < 32; ++i) u[i] = Bs[i*32 + c];                     \
            _Pragma("unroll")                                                     \
            for (int r = 0; r < 32; ++r) {                                        \
                float x = u[r] * rlane(invd_own, r);                              \
                u[r] = x;                                                         \
                _Pragma("unroll")                                                 \
                for (int i = r+1; i < 32; ++i)                                    \
                    u[i] = fmaf(-rlane(Lcol[i], r), x, u[i]);                     \
            }                                                                     \
            if (OWNED) {                                                          \
                float* ct = Cg + (size_t)t*1024;                                  \
                _Pragma("unroll")                                                 \
                for (int rr = 0; rr < 16; ++rr) {                                 \
                    float val = h ? u[16+rr] : u[rr];                             \
                    ct[(h*16+rr)*32 + c] = val;                                   \
                }                                                                 \
            }                                                                     \
            float f0[8], f1[8];                                                   \
            _Pragma("unroll")                                                     \
            for (int j = 0; j < 8; ++j) {                                         \
                f0[j] = h ? u[8+j]  : u[j];                                       \
                f1[j] = h ? u[24+j] : u[16+j];                                    \
            }                                                                     \
            bf16x8 A0h, A0l, A1h, A1l;                                            \
            _Pragma("unroll")                                                     \
            for (int j = 0; j < 8; ++j) {                                         \
                unsigned short hh0 = f2bf_c(f0[j]);                               \
                A0h[j] = (short)hh0; A0l[j] = (short)f2bf_c(f0[j] - bf2f(hh0));   \
                unsigned short hh1 = f2bf_c(f1[j]);                               \
                A1h[j] = (short)hh1; A1l[j] = (short)f2bf_c(f1[j] - bf2f(hh1));   \
            }                                                                     \
            f32x16 d;                                                             \
            _Pragma("unroll")                                                     \
            for (int q = 0; q < 16; ++q) d[q] = 0.f;                              \
            d = MFMA32(A0h, A0h, d);                                              \
            d = MFMA32(A0h, A0l, d);                                              \
            d = MFMA32(A0l, A0h, d);                                              \
            d = MFMA32(A1h, A1h, d);                                              \
            d = MFMA32(A1h, A1l, d);                                              \
            d = MFMA32(A1l, A1h, d);                                              \
            float dsw[16];                                                        \
            _Pragma("unroll")                                                     \
            for (int q = 0; q < 16; ++q) dsw[q] = __shfl_xor(d[q], 32);           \
            _Pragma("unroll")                                                     \
            for (int i = 0; i < 32; ++i) {                                        \
                const int q  = (i & 3) + ((i >> 3) << 2);                         \
                const int hh = (i >> 2) & 1;                                      \
                s[i] -= (h == hh) ? d[q] : dsw[q];                                \
            }                                                                     \
        }                                                                         \
        float pivk = 1.f;                                                         \
        _Pragma("unroll")                                                         \
        for (int j = 0; j < 32; ++j) {                                            \
            float sjj = rlane(s[j], j);                                           \
            float inv = __builtin_amdgcn_rsqf(sjj);                               \
            pivk = (c == j) ? sjj : pivk;                                         \
            float inv2 = inv * inv;                                               \
            float ljc = (c > j) ? s[j] * inv2 : 0.f;                              \
            invd_own = (c == j) ? inv : invd_own;                                 \
            _Pragma("unroll")                                                     \
            for (int i = j; i < 32; ++i) s[i] = fmaf(-rlane(s[i], j), ljc, s[i]); \
        }                                                                         \
        if (OWNED) logacc += __logf(pivk);                                        \
        _Pragma("unroll")                                                         \
        for (int i = 0; i < 32; ++i) Lcol[i] = s[i] * invd_own;                   \
        if (OWNED) {                                                              \
            float* lt = Lg + (size_t)t*1024 + c*32 + h*16;                        \
            _Pragma("unroll")                                                     \
            for (int q = 0; q < 4; ++q) {                                         \
                float4 v4 = make_float4(h ? Lcol[16+4*q]   : Lcol[4*q],           \
                                        h ? Lcol[16+4*q+1] : Lcol[4*q+1],         \
                                        h ? Lcol[16+4*q+2] : Lcol[4*q+2],         \
                                        h ? Lcol[16+4*q+3] : Lcol[4*q+3]);        \
                *(float4*)(lt + 4*q) = v4;                                        \
            }                                                                     \
        }                                                                         \
    }

__global__ __launch_bounds__(64)
void chol_scan8(const float* __restrict__ AA, float* __restrict__ Lg,
                float* __restrict__ Cg, const float* __restrict__ cw,
                float* __restrict__ logsum, int K, int W)
{
    const int lane = threadIdx.x;
    const int c = lane & 31;
    const int h = lane >> 5;
    const int own0 = blockIdx.x * K;
    const int own1 = min(TT, own0 + K);
    const int t0 = max(0, own0 - W);

    __shared__ float Bs[1024];
#pragma unroll
    for (int i = 0; i < 16; ++i) Bs[i*64 + lane] = cw[OFF_B + i*64 + lane];
    __syncthreads();

    float Lcol[32], s[32], u[32];
    float invd_own = 0.f, logacc = 0.f;

    for (int t = t0; t < own0; ++t) CHOL_STEP2(false)
    for (int t = own0; t < own1; ++t) CHOL_STEP2(true)

    // lane c holds sum over owned steps of log(pivot_c); butterfly within 32
#pragma unroll
    for (int sft = 16; sft > 0; sft >>= 1) logacc += __shfl_xor(logacc, sft);
    if (lane == 0) atomicAdd(logsum, logacc * 0.5f);
}

// ---------------- chunked forward bidiagonal solve (L col-major, C = X row-major) -------
__global__ __launch_bounds__(64)
void fwd_solve_kernel(const float* __restrict__ Lg, const float* __restrict__ Cg,
                      const float* __restrict__ bv, float* __restrict__ xout,
                      int K, int W)
{
    const int lane = threadIdx.x;
    const int r = lane & 31, h = lane >> 5;
    const int own0 = blockIdx.x * K;
    const int own1 = min(TT, own0 + K);
    const int t0 = max(0, own0 - W);
    float xprev = 0.f;
    for (int t = t0; t < own1; ++t) {
        const float* lt = Lg + (size_t)t * 1024;
        float Lr[32];
#pragma unroll
        for (int j = 0; j < DZ; ++j) Lr[j] = lt[j*32 + r];
        const float inv = __builtin_amdgcn_rcpf(Lr[r]);
        float v = bv[t*DZ + r];
        if (t > t0) {
            const float* ct = Cg + (size_t)t * 1024;
            float Cr[32];
#pragma unroll
            for (int cc = 0; cc < DZ; ++cc) Cr[cc] = ct[cc*32 + r];
#pragma unroll
            for (int cc = 0; cc < DZ; ++cc) v = fmaf(-Cr[cc], __shfl(xprev, cc), v);
        }
        float xv = 0.f;
#pragma unroll
        for (int rr = 0; rr < DZ; ++rr) {
            float cand = v * inv;
            float xb = __shfl(cand, rr);
            if (r == rr) xv = cand;
            if (r > rr) v = fmaf(-Lr[rr], xb, v);
        }
        xprev = xv;
        if (t >= own0 && h == 0) xout[t*DZ + r] = xv;
    }
}

// ---------------- chunked backward solve (two RHS) + sample + entropy ------------------
__global__ __launch_bounds__(64)
void bwd_solve_kernel(const float* __restrict__ Lg, const float* __restrict__ Cg,
                      const float* __restrict__ b1, const float* __restrict__ b2,
                      float* __restrict__ outSample, const float* __restrict__ logsum,
                      int K, int W)
{
    const int lane = threadIdx.x;
    const int k = lane & 31, h = lane >> 5;
    const int own0 = blockIdx.x * K;
    const int own1 = min(TT, own0 + K);
    const int tS = min(TT - 1, own1 - 1 + W);
    if (blockIdx.x == 0 && lane == 0) {
        // entropy (logsum complete: chol kernel precedes this one)
        outSample[TT*DZ] = (logsum[0] - 2270.3016531274763f) / 409600.0f;
    }
    float x1p = 0.f, x2p = 0.f;
    for (int t = tS; t >= own0; --t) {
        const float* lt = Lg + (size_t)t * 1024;
        float Lc[32];
#pragma unroll
        for (int q = 0; q < 8; ++q) {
            float4 v4 = *(const float4*)(lt + k*32 + 4*q);
            Lc[4*q] = v4.x; Lc[4*q+1] = v4.y; Lc[4*q+2] = v4.z; Lc[4*q+3] = v4.w;
        }
        const float inv = __builtin_amdgcn_rcpf(Lc[k]);
        float v1 = b1[t*DZ + k], v2 = b2[t*DZ + k];
        if (t < tS) {
            const float* ct = Cg + (size_t)(t+1) * 1024;
            float Cc[32];
#pragma unroll
            for (int q = 0; q < 8; ++q) {
                float4 w4 = *(const float4*)(ct + k*32 + 4*q);
                Cc[4*q] = w4.x; Cc[4*q+1] = w4.y; Cc[4*q+2] = w4.z; Cc[4*q+3] = w4.w;
            }
#pragma unroll
            for (int cc = 0; cc < DZ; ++cc) {
                float a1 = __shfl(x1p, cc), a2 = __shfl(x2p, cc);
                v1 = fmaf(-Cc[cc], a1, v1); v2 = fmaf(-Cc[cc], a2, v2);
            }
        }
        float x1 = 0.f, x2 = 0.f;
#pragma unroll
        for (int rr = DZ-1; rr >= 0; --rr) {
            float c1 = v1 * inv, c2 = v2 * inv;
            float xb1 = __shfl(c1, rr), xb2 = __shfl(c2, rr);
            if (k == rr) { x1 = c1; x2 = c2; }
            if (k < rr) { v1 = fmaf(-Lc[rr], xb1, v1); v2 = fmaf(-Lc[rr], xb2, v2); }
        }
        x1p = x1; x2p = x2;
        if (t >= own0 && h == 0) outSample[t*DZ + k] = x1 + x2;
    }
}

// ---------------- launch ----------------
extern "C" void kernel_launch(void* const* d_in, const int* in_sizes, int n_in,
                              void* d_out, int out_size, void* d_ws, size_t ws_size,
                              hipStream_t stream)
{
    (void)in_sizes; (void)n_in; (void)out_size; (void)ws_size;
    const float* x        = (const float*)d_in[0];
    const float* norm     = (const float*)d_in[1];
    const float* A        = (const float*)d_in[2];
    const float* QinvChol = (const float*)d_in[3];
    const float* Q0invChol= (const float*)d_in[4];
    const float* Wm_in = (const float*)d_in[5];  const float* bm_in = (const float*)d_in[6];
    const float* Wm_h1 = (const float*)d_in[7];  const float* bm_h1 = (const float*)d_in[8];
    const float* Wm_h3 = (const float*)d_in[9];  const float* bm_h3 = (const float*)d_in[10];
    const float* Wm_out= (const float*)d_in[11]; const float* bm_out= (const float*)d_in[12];
    const float* Wc_in = (const float*)d_in[13]; const float* bc_in = (const float*)d_in[14];
    const float* Wc_h1 = (const float*)d_in[15]; const float* bc_h1 = (const float*)d_in[16];
    const float* Wc_h3 = (const float*)d_in[17]; const float* bc_h3 = (const float*)d_in[18];
    const float* Wc_out= (const float*)d_in[19]; const float* bc_out= (const float*)d_in[20];

    float* ws    = (float*)d_ws;
    float* out   = (float*)d_out;
    float* cw    = ws;
    float* Lbuf  = ws + OFF_ACT0;
    float* Cbuf  = ws + OFF_ACT1;
    float* covb  = ws + OFF_AAB;
    float* meanb = ws + OFF_MEANB;
    float* lamMu = ws + OFF_LAMMU;
    float* ib    = ws + OFF_IBV;
    float* logsum = ws + OFF_LOGSUM;

    // 4 f16 activation slots, carved from ACT0/ACT1 regions
    _Float16* s0 = (_Float16*)(ws + OFF_ACT0);
    _Float16* s1 = s0 + 8388608;
    _Float16* s2 = (_Float16*)(ws + OFF_ACT1);
    _Float16* s3 = s2 + 8388608;
    _Float16* xh = (_Float16*)(ws + OFF_XB);

    const long OWmi = OFF_WB;
    const long OWm1 = OWmi + 262144;
    const long OWm3 = OWm1 + 1048576;
    const long OWmo = OWm3 + 1048576;
    const long OWci = OWmo + 32768;
    const long OWc1 = OWci + 262144;
    const long OWc3 = OWc1 + 1048576;
    const long OWco = OWc3 + 1048576;
    #define WH(o) ((_Float16*)(ws + (o)))

    setup_kernel<<<dim3(1), dim3(1024), 0, stream>>>(A, QinvChol, Q0invChol, cw);

    SplitArgs sa;
    sa.seg[0] = { x,      xh,       2097152 };
    sa.seg[1] = { Wm_in,  WH(OWmi), 262144 };
    sa.seg[2] = { Wm_h1,  WH(OWm1), 1048576 };
    sa.seg[3] = { Wm_h3,  WH(OWm3), 1048576 };
    sa.seg[4] = { Wm_out, WH(OWmo), 32768 };
    sa.seg[5] = { Wc_in,  WH(OWci), 262144 };
    sa.seg[6] = { Wc_h1,  WH(OWc1), 1048576 };
    sa.seg[7] = { Wc_h3,  WH(OWc3), 1048576 };
    sa.seg[8] = { Wc_out, WH(OWco), 1048576 };
    split_all<<<dim3(2048, 9), dim3(256), 0, stream>>>(sa);

    const dim3 gM(8, 64, 2), blk(256);
    // L1: x -> s0 (mean h1) / s1 (cov h1)
    mgemm2<<<gM, blk, 0, stream>>>(xh, xh, WH(OWmi), WH(OWci), bm_in, bc_in, s0, s1, 1024, 256);
    // L2: s0 -> s2 / s1 -> s3
    mgemm2<<<gM, blk, 0, stream>>>(s0, s1, WH(OWm1), WH(OWc1), bm_h1, bc_h1, s2, s3, 1024, 1024);
    // L3: s2 -> s0 / s3 -> s1
    mgemm2<<<gM, blk, 0, stream>>>(s2, s3, WH(OWm3), WH(OWc3), bm_h3, bc_h3, s0, s1, 1024, 1024);
    // combined heads: cov f32 head (x<8) + mean N=32 head (x==8)
    mgemm_heads<<<dim3(9, 64), blk, 0, stream>>>(s1, WH(OWco), bc_out, covb,
                                                 s0, WH(OWmo), bm_out, meanb, 1024, 1024);

    build_blocks_kernel<<<dim3(TT), dim3(256), 0, stream>>>(covb, meanb, lamMu, cw);

    // chol: K=2/W=1 -> 12288 wave-steps at 4 waves/SIMD
    chol_scan8<<<dim3(TT/2), dim3(64), 0, stream>>>(covb, Lbuf, Cbuf, cw, logsum, 2, 1);
    fwd_solve_kernel<<<dim3(TT/8), dim3(64), 0, stream>>>(Lbuf, Cbuf, lamMu, ib, 8, 3);
    bwd_solve_kernel<<<dim3(TT/8), dim3(64), 0, stream>>>(Lbuf, Cbuf, ib, norm, out, logsum, 8, 3);
}